// Round 2
// baseline (322.545 us; speedup 1.0000x reference)
//
#include <hip/hip_runtime.h>

typedef __attribute__((ext_vector_type(4))) float f32x4;
typedef __attribute__((ext_vector_type(8))) __bf16 bf16x8;
typedef __attribute__((ext_vector_type(4))) __bf16 bf16x4;

__device__ __forceinline__ void gload_lds16(const __bf16* g, __bf16* l) {
  __builtin_amdgcn_global_load_lds(
      (const __attribute__((address_space(1))) unsigned int*)(g),
      (__attribute__((address_space(3))) unsigned int*)(l), 16, 0, 0);
}

// ---------------- prep: weight transposes + x convert + pad_or, one launch --------
__global__ __launch_bounds__(256) void prep(
    const float* __restrict__ Wq, const float* __restrict__ Wk,
    const float* __restrict__ Wv, const float* __restrict__ Wo,
    const float4* __restrict__ x, const unsigned long long* __restrict__ pad,
    __bf16* __restrict__ Wqkvt, __bf16* __restrict__ Wot,
    bf16x4* __restrict__ xb, unsigned char* __restrict__ pad64) {
  const int bx = blockIdx.x, by = blockIdx.y;
  const int tx = threadIdx.x, ty = threadIdx.y;
  const int tid = ty * 32 + tx;
  if (bx >= 160) {
    int i = ((bx - 160) * 64 + by) * 256 + tid;
    float4 v = x[i];
    bf16x4 o = {(__bf16)v.x, (__bf16)v.y, (__bf16)v.z, (__bf16)v.w};
    xb[i] = o;
    return;
  }
  if (bx == 0 && by == 0 && tid < 64) {
    unsigned long long acc = 0;
#pragma unroll
    for (int i = 0; i < 8; ++i) acc |= pad[tid * 8 + i];
    pad64[tid] = (acc != 0) ? 1 : 0;
  }
  __shared__ float t[32][33];
  const float* src; __bf16* dst; int ss, c0;
  if (bx < 64)      { src = Wq; dst = Wqkvt;                       ss = 2048; c0 = bx * 32; }
  else if (bx < 80) { src = Wk; dst = Wqkvt + (size_t)2048 * 2048; ss = 512;  c0 = (bx - 64) * 32; }
  else if (bx < 96) { src = Wv; dst = Wqkvt + (size_t)2560 * 2048; ss = 512;  c0 = (bx - 80) * 32; }
  else              { src = Wo; dst = Wot;                         ss = 2048; c0 = (bx - 96) * 32; }
  const int r0 = by * 32;
#pragma unroll
  for (int i = ty; i < 32; i += 8)
    t[i][tx] = src[(size_t)(r0 + i) * ss + c0 + tx];
  __syncthreads();
#pragma unroll
  for (int i = ty; i < 32; i += 8)
    dst[(size_t)(c0 + i) * 2048 + r0 + tx] = (__bf16)t[tx][i];
}

// ---------------- QKV GEMM, 256x256 tile, BK=64, double-buffered counted-vmcnt ----
// C = xb[4096][2048] * Wqkvt[3072][2048]^T. Grid: 192 blocks (12 n-tiles x 16 m-tiles,
// XCD-bijective swizzle), 512 threads = 8 waves (2M x 4N), per-wave output 128x64.
// LDS: 2 x (A 256x64 + B 256x64) bf16 = 128 KiB dynamic.
// Schedule per K-tile t: vmcnt(8) [tile t landed; t+1 in flight] -> s_barrier ->
// ds_read+64 MFMA/wave -> lgkmcnt(0) -> s_barrier [buf free] -> stage t+2 into buf[t&1].
// Race-free: stage of t+2 targets the buffer ONLY after all waves' reads of t complete;
// vmcnt FIFO retire (m135) makes vmcnt(8) guarantee tile t while t+1 stays in flight.
// T2 granule swizzle g^=(row&7): linear LDS dest (global_load_lds), inverse-swizzled
// global source, swizzled ds_read -> conflict-free b128 reads.
__device__ __forceinline__ void stage_t(const __bf16* aS, const __bf16* bS,
                                        __bf16* Ab, __bf16* Bb, int wb8, size_t kt) {
#pragma unroll
  for (int l = 0; l < 4; ++l)
    gload_lds16(aS + (size_t)l * 131072 + kt, Ab + l * 4096 + wb8);
#pragma unroll
  for (int l = 0; l < 4; ++l)
    gload_lds16(bS + (size_t)l * 131072 + kt, Bb + l * 4096 + wb8);
}

__global__ __launch_bounds__(512, 2) void gemm_qkv256(
    const __bf16* __restrict__ A, const __bf16* __restrict__ Bt,
    __bf16* __restrict__ Qb, __bf16* __restrict__ Kb, __bf16* __restrict__ Vt) {
  extern __shared__ __bf16 smem[];
  const int K = 2048;
  const int tid = threadIdx.x;
  const int lane = tid & 63, w = tid >> 6;
  const int c15 = lane & 15, quad = lane >> 4;
  const int wm = w >> 2, wn = w & 3;
  const int id = blockIdx.x;
  const int swz = (id & 7) * 24 + (id >> 3);   // bijective: 192 = 8*24
  const int m0 = (swz / 12) * 256, n0 = (swz % 12) * 256;

  // staging: thread covers granule (l*512+tid); row = l*64 + tid/8, swizzled col const.
  const int srow = tid >> 3;
  const int scol = ((tid & 7) ^ (srow & 7)) * 8;
  const __bf16* aSrc = A + (size_t)(m0 + srow) * K + scol;
  const __bf16* bSrc = Bt + (size_t)(n0 + srow) * K + scol;
  const int wb8 = (tid & 448) * 8;   // wave-uniform LDS base (elems)
  __bf16* A0 = smem;
  __bf16* B0 = smem + 16384;
  __bf16* A1 = smem + 32768;
  __bf16* B1 = smem + 49152;

  f32x4 acc[8][4] = {};

  stage_t(aSrc, bSrc, A0, B0, wb8, 0);
  stage_t(aSrc, bSrc, A1, B1, wb8, 64);

  for (int t = 0; t < 32; ++t) {
    __bf16* Ab = smem + (t & 1) * 32768;
    __bf16* Bb = Ab + 16384;
    if (t < 31) asm volatile("s_waitcnt vmcnt(8)" ::: "memory");
    else        asm volatile("s_waitcnt vmcnt(0)" ::: "memory");
    __builtin_amdgcn_s_barrier();
    __builtin_amdgcn_sched_barrier(0);

    bf16x8 bF[4][2];
#pragma unroll
    for (int j = 0; j < 4; ++j) {
      int RB = wn * 64 + j * 16 + c15;
#pragma unroll
      for (int h = 0; h < 2; ++h)
        bF[j][h] = *(const bf16x8*)(Bb + RB * 64 + (((h * 4 + quad) ^ (RB & 7)) * 8));
    }
    __builtin_amdgcn_s_setprio(1);
#pragma unroll
    for (int i = 0; i < 8; ++i) {
      int RA = wm * 128 + i * 16 + c15;
      bf16x8 a0 = *(const bf16x8*)(Ab + RA * 64 + ((quad ^ (RA & 7)) * 8));
      bf16x8 a1 = *(const bf16x8*)(Ab + RA * 64 + (((4 + quad) ^ (RA & 7)) * 8));
#pragma unroll
      for (int j = 0; j < 4; ++j) {
        acc[i][j] = __builtin_amdgcn_mfma_f32_16x16x32_bf16(a0, bF[j][0], acc[i][j], 0, 0, 0);
        acc[i][j] = __builtin_amdgcn_mfma_f32_16x16x32_bf16(a1, bF[j][1], acc[i][j], 0, 0, 0);
      }
    }
    __builtin_amdgcn_s_setprio(0);
    __builtin_amdgcn_sched_barrier(0);
    asm volatile("s_waitcnt lgkmcnt(0)" ::: "memory");
    __builtin_amdgcn_s_barrier();
    __builtin_amdgcn_sched_barrier(0);
    if (t < 30) stage_t(aSrc, bSrc, Ab, Bb, wb8, (size_t)(t + 2) * 64);
  }

  // ---- epilogue: per-wave 16KB LDS chunk (buffers are free after final barrier) ----
  const int b = m0 >> 11;
  const int s0 = m0 & 2047;
  const int colbase = n0 + wn * 64;
  __bf16* st = smem + w * 8192;

  if (colbase >= 2560) {
    // V: stage transposed [d 0..63][s 0..127], granule-XOR swizzled.
#pragma unroll
    for (int i = 0; i < 8; ++i)
#pragma unroll
      for (int j = 0; j < 4; ++j) {
        int dl = j * 16 + c15;
        int gr = (i * 2 + (quad >> 1)) ^ (dl & 7);
        bf16x4 o = {(__bf16)acc[i][j][0], (__bf16)acc[i][j][1],
                    (__bf16)acc[i][j][2], (__bf16)acc[i][j][3]};
        *(bf16x4*)(st + dl * 128 + gr * 8 + (quad & 1) * 4) = o;
      }
    __bf16* VtH = Vt + (((size_t)b * 4 + ((colbase - 2560) >> 7)) * 128) * 2048 +
                  (size_t)(colbase & 127) * 2048 + s0 + wm * 128;
#pragma unroll
    for (int pass = 0; pass < 16; ++pass) {
      int d = pass * 4 + quad;
      int gp = (c15 & 8) | ((c15 ^ d) & 7);
      *(bf16x8*)(VtH + (size_t)d * 2048 + c15 * 8) =
          *(const bf16x8*)(st + d * 128 + gp * 8);
    }
  } else {
    // Q/K: stage [s 0..127][d 0..63], granule-XOR swizzled, coalesced 128B rows out.
#pragma unroll
    for (int i = 0; i < 8; ++i)
#pragma unroll
      for (int j = 0; j < 4; ++j)
#pragma unroll
        for (int r = 0; r < 4; ++r) {
          int s = i * 16 + quad * 4 + r;
          int dl = j * 16 + c15;
          st[s * 64 + (((dl >> 3) ^ (s & 7)) * 8) + (dl & 7)] = (__bf16)acc[i][j][r];
        }
    __bf16* dstH = (colbase < 2048)
        ? Qb + (((size_t)b * 16 + (colbase >> 7)) * 2048) * 128 + (colbase & 127)
        : Kb + (((size_t)b * 4 + ((colbase - 2048) >> 7)) * 2048) * 128 + (colbase & 127);
    dstH += (size_t)(s0 + wm * 128) * 128;
    const int g = lane & 7, sl = lane >> 3;
#pragma unroll
    for (int it = 0; it < 16; ++it) {
      int s = it * 8 + sl;
      *(bf16x8*)(dstH + (size_t)s * 128 + g * 8) =
          *(const bf16x8*)(st + s * 64 + ((g ^ (s & 7)) * 8));
    }
  }
}

// ---------------- RMSNorm + RoPE, in-place on bf16 Q/K ----------------
__global__ __launch_bounds__(256) void norm_rope(
    __bf16* __restrict__ Qb, __bf16* __restrict__ Kb,
    const float* __restrict__ qw, const float* __restrict__ kw,
    const float* __restrict__ cosT, const float* __restrict__ sinT) {
  const int tid = threadIdx.x, w = tid >> 6, lane = tid & 63;
  const int v = blockIdx.x * 4 + w;
  const bool isQ = v < 65536;
  __bf16* base = isQ ? Qb + (size_t)v * 128 : Kb + (size_t)(v - 65536) * 128;
  const int s = v & 2047;
  float x1 = (float)base[lane], x2 = (float)base[lane + 64];
  float ss = x1 * x1 + x2 * x2;
#pragma unroll
  for (int d = 32; d; d >>= 1) ss += __shfl_xor(ss, d);
  float rn = rsqrtf(ss * (1.0f / 128.0f) + 1e-8f);
  const float* wt = isQ ? qw : kw;
  float n1 = x1 * rn * (1.0f + wt[lane]);
  float n2 = x2 * rn * (1.0f + wt[lane + 64]);
  float c1 = cosT[s * 128 + lane], c2 = cosT[s * 128 + 64 + lane];
  float s1 = sinT[s * 128 + lane], s2 = sinT[s * 128 + 64 + lane];
  const float QSC = 0.08838834764831845f * 1.4426950408889634f;  // scale * log2(e)
  float post = isQ ? QSC : 1.0f;
  base[lane]      = (__bf16)((n1 * c1 - n2 * s1) * post);
  base[lane + 64] = (__bf16)((n2 * c2 + n1 * s2) * post);
}

// ---------------- m97-style bf16 GEMM (output projection) ----------------
__global__ __launch_bounds__(256) void gemm_bt(const __bf16* __restrict__ A,
                                               const __bf16* __restrict__ Bt,
                                               float* __restrict__ C,
                                               int M, int N, int K) {
  __shared__ __align__(16) __bf16 As[128 * 32];
  __shared__ __align__(16) __bf16 Bs[128 * 32];
  const int tid = threadIdx.x;
  const int lane = tid & 63;
  const int c15 = lane & 15, quad = lane >> 4;
  const int wm = ((tid >> 6) & 1) * 64;
  const int wn = (tid >> 7) * 64;
  const int m0 = blockIdx.y * 128, n0 = blockIdx.x * 128;
  const int wbase = tid & 192;

  f32x4 acc[4][4] = {};

  const int row0 = tid >> 2, cc0 = (tid & 3) * 8;
  const int row1 = (tid + 256) >> 2;
  const __bf16* a0 = A + (size_t)(m0 + row0) * K + cc0;
  const __bf16* a1 = A + (size_t)(m0 + row1) * K + cc0;
  const __bf16* b0 = Bt + (size_t)(n0 + row0) * K + cc0;
  const __bf16* b1 = Bt + (size_t)(n0 + row1) * K + cc0;
  __bf16* lA0 = As + (size_t)wbase * 8;
  __bf16* lA1 = As + (size_t)(256 + wbase) * 8;
  __bf16* lB0 = Bs + (size_t)wbase * 8;
  __bf16* lB1 = Bs + (size_t)(256 + wbase) * 8;

  for (int k0 = 0; k0 < K; k0 += 32) {
    gload_lds16(a0 + k0, lA0);
    gload_lds16(a1 + k0, lA1);
    gload_lds16(b0 + k0, lB0);
    gload_lds16(b1 + k0, lB1);
    __syncthreads();
    bf16x8 af[4], bfr[4];
#pragma unroll
    for (int i = 0; i < 4; ++i) {
      af[i]  = *(const bf16x8*)(As + (wm + i * 16 + c15) * 32 + quad * 8);
      bfr[i] = *(const bf16x8*)(Bs + (wn + i * 16 + c15) * 32 + quad * 8);
    }
#pragma unroll
    for (int i = 0; i < 4; ++i)
#pragma unroll
      for (int j = 0; j < 4; ++j)
        acc[i][j] = __builtin_amdgcn_mfma_f32_16x16x32_bf16(af[i], bfr[j], acc[i][j], 0, 0, 0);
    __syncthreads();
  }

#pragma unroll
  for (int i = 0; i < 4; ++i) {
    int r0 = m0 + wm + i * 16 + quad * 4;
#pragma unroll
    for (int j = 0; j < 4; ++j) {
      int cc = n0 + wn + j * 16 + c15;
#pragma unroll
      for (int r = 0; r < 4; ++r)
        C[(size_t)(r0 + r) * N + cc] = acc[i][j][r];
    }
  }
}

// ---------------- Flash attention v4: 32 q-rows per wave ----------------
__global__ __launch_bounds__(256) void attn(
    const __bf16* __restrict__ Qb, const __bf16* __restrict__ Kb,
    const __bf16* __restrict__ Vt, const unsigned char* __restrict__ pad,
    const unsigned char* __restrict__ pad64, const int* __restrict__ winp,
    __bf16* __restrict__ O) {
  const int S = 2048;
  __shared__ __align__(16) __bf16 Ks[64 * 128];
  __shared__ __align__(16) __bf16 Vs[128 * 64];
  __shared__ __align__(16) __bf16 Ps[4 * 32 * 72];
  const int tid = threadIdx.x, w = tid >> 6, lane = tid & 63;
  const int c15 = lane & 15, quad = lane >> 4;
  const int b = blockIdx.z;
  const int bx = (b == 0) ? blockIdx.x : (gridDim.x - 1 - blockIdx.x);
  const int q0 = ((int)gridDim.x - 1 - bx) * 32;
  const int kv = blockIdx.y;
  const int h = kv * 4 + w;
  const int W = *winp;
  const unsigned char* padb = pad + (size_t)b * S;
  const unsigned char* pad64b = pad64 + b * 32;
  const __bf16* Qh = Qb + (((size_t)b * 16 + h) * S) * 128;
  const __bf16* Kh = Kb + (((size_t)b * 4 + kv) * S) * 128;
  const __bf16* Vh = Vt + (((size_t)b * 4 + kv) * 128) * (size_t)S;
  __bf16* Pw = Ps + w * 32 * 72;

  bf16x8 qf0[4], qf1[4];
#pragma unroll
  for (int c = 0; c < 4; ++c) {
    qf0[c] = *(const bf16x8*)(Qh + (size_t)(q0 + c15) * 128 + c * 32 + quad * 8);
    qf1[c] = *(const bf16x8*)(Qh + (size_t)(q0 + 16 + c15) * 128 + c * 32 + quad * 8);
  }

  f32x4 acc0[8] = {}, acc1[8] = {};
  float lsum0[4] = {0.f, 0.f, 0.f, 0.f};
  float lsum1[4] = {0.f, 0.f, 0.f, 0.f};

  const int krow_i = lane >> 4, kch = lane & 15;
  const int vrow_i = lane >> 3, vch = lane & 7;

  int kb0 = q0 - W; if (kb0 < 0) kb0 = 0; kb0 &= ~63;

  for (int kb = kb0; kb <= q0 + 31; kb += 64) {
    __syncthreads();
#pragma unroll
    for (int i = 0; i < 4; ++i) {
      int row = w * 16 + i * 4 + krow_i;
      gload_lds16(Kh + (size_t)(kb + row) * 128 + ((kch ^ (row & 15)) * 8),
                  Ks + (w * 16 + i * 4) * 128);
    }
#pragma unroll
    for (int i = 0; i < 4; ++i) {
      int row = w * 32 + i * 8 + vrow_i;
      gload_lds16(Vh + (size_t)row * S + kb + ((vch ^ (row & 7)) * 8),
                  Vs + (w * 32 + i * 8) * 64);
    }
    __syncthreads();

    f32x4 sf0[4], sf1[4];
#pragma unroll
    for (int nb = 0; nb < 4; ++nb) {
      f32x4 ca = {}, cb = {};
#pragma unroll
      for (int c = 0; c < 4; ++c) {
        bf16x8 kf = *(const bf16x8*)(Ks + (nb * 16 + c15) * 128 + (((c * 4 + quad) ^ c15) * 8));
        ca = __builtin_amdgcn_mfma_f32_16x16x32_bf16(qf0[c], kf, ca, 0, 0, 0);
        cb = __builtin_amdgcn_mfma_f32_16x16x32_bf16(qf1[c], kf, cb, 0, 0, 0);
      }
      sf0[nb] = ca; sf1[nb] = cb;
    }

    const bool fast = (kb + 63 <= q0) && (q0 + 31 - kb <= W) && (pad64b[kb >> 6] == 0);
    if (fast) {
#pragma unroll
      for (int r = 0; r < 4; ++r) {
        float a0 = exp2f(sf0[0][r]), a1 = exp2f(sf0[1][r]);
        float a2 = exp2f(sf0[2][r]), a3 = exp2f(sf0[3][r]);
        lsum0[r] += (a0 + a1) + (a2 + a3);
        int pr = (quad * 4 + r) * 72 + c15;
        Pw[pr] = (__bf16)a0; Pw[pr + 16] = (__bf16)a1;
        Pw[pr + 32] = (__bf16)a2; Pw[pr + 48] = (__bf16)a3;
        float b0 = exp2f(sf1[0][r]), b1 = exp2f(sf1[1][r]);
        float b2 = exp2f(sf1[2][r]), b3 = exp2f(sf1[3][r]);
        lsum1[r] += (b0 + b1) + (b2 + b3);
        int qr = pr + 16 * 72;
        Pw[qr] = (__bf16)b0; Pw[qr + 16] = (__bf16)b1;
        Pw[qr + 32] = (__bf16)b2; Pw[qr + 48] = (__bf16)b3;
      }
    } else {
#pragma unroll
      for (int r = 0; r < 4; ++r) {
        const int qi0 = q0 + quad * 4 + r;
        const int qi1 = qi0 + 16;
        float p0[4], p1[4];
#pragma unroll
        for (int nb = 0; nb < 4; ++nb) {
          int ki = kb + nb * 16 + c15;
          bool okp = (padb[ki] == 0);
          bool ok0 = (ki <= qi0) && ((qi0 - ki) <= W) && okp;
          bool ok1 = (ki <= qi1) && ((qi1 - ki) <= W) && okp;
          float e0 = exp2f(sf0[nb][r]);
          float e1 = exp2f(sf1[nb][r]);
          p0[nb] = ok0 ? e0 : 0.0f;
          p1[nb] = ok1 ? e1 : 0.0f;
        }
        lsum0[r] += (p0[0] + p0[1]) + (p0[2] + p0[3]);
        lsum1[r] += (p1[0] + p1[1]) + (p1[2] + p1[3]);
        int pr = (quad * 4 + r) * 72 + c15;
        Pw[pr] = (__bf16)p0[0]; Pw[pr + 16] = (__bf16)p0[1];
        Pw[pr + 32] = (__bf16)p0[2]; Pw[pr + 48] = (__bf16)p0[3];
        int qr = pr + 16 * 72;
        Pw[qr] = (__bf16)p1[0]; Pw[qr + 16] = (__bf16)p1[1];
        Pw[qr + 32] = (__bf16)p1[2]; Pw[qr + 48] = (__bf16)p1[3];
      }
    }

    bf16x8 pf00 = *(const bf16x8*)(Pw + c15 * 72 + quad * 8);
    bf16x8 pf01 = *(const bf16x8*)(Pw + c15 * 72 + 32 + quad * 8);
    bf16x8 pf10 = *(const bf16x8*)(Pw + (16 + c15) * 72 + quad * 8);
    bf16x8 pf11 = *(const bf16x8*)(Pw + (16 + c15) * 72 + 32 + quad * 8);
#pragma unroll
    for (int nb = 0; nb < 8; ++nb) {
      int row = nb * 16 + c15;
      bf16x8 vf0 = *(const bf16x8*)(Vs + row * 64 + ((quad ^ (c15 & 7)) * 8));
      bf16x8 vf1 = *(const bf16x8*)(Vs + row * 64 + (((4 + quad) ^ (c15 & 7)) * 8));
      acc0[nb] = __builtin_amdgcn_mfma_f32_16x16x32_bf16(pf00, vf0, acc0[nb], 0, 0, 0);
      acc0[nb] = __builtin_amdgcn_mfma_f32_16x16x32_bf16(pf01, vf1, acc0[nb], 0, 0, 0);
      acc1[nb] = __builtin_amdgcn_mfma_f32_16x16x32_bf16(pf10, vf0, acc1[nb], 0, 0, 0);
      acc1[nb] = __builtin_amdgcn_mfma_f32_16x16x32_bf16(pf11, vf1, acc1[nb], 0, 0, 0);
    }
  }

#pragma unroll
  for (int r = 0; r < 4; ++r) {
    lsum0[r] += __shfl_xor(lsum0[r], 1);
    lsum0[r] += __shfl_xor(lsum0[r], 2);
    lsum0[r] += __shfl_xor(lsum0[r], 4);
    lsum0[r] += __shfl_xor(lsum0[r], 8);
    lsum1[r] += __shfl_xor(lsum1[r], 1);
    lsum1[r] += __shfl_xor(lsum1[r], 2);
    lsum1[r] += __shfl_xor(lsum1[r], 4);
    lsum1[r] += __shfl_xor(lsum1[r], 8);
  }
  float inv0[4], inv1[4];
#pragma unroll
  for (int r = 0; r < 4; ++r) { inv0[r] = 1.0f / lsum0[r]; inv1[r] = 1.0f / lsum1[r]; }
#pragma unroll
  for (int nb = 0; nb < 8; ++nb)
#pragma unroll
    for (int r = 0; r < 4; ++r) {
      size_t idx = ((size_t)b * S + q0 + quad * 4 + r) * 2048 + h * 128 + nb * 16 + c15;
      O[idx] = (__bf16)(acc0[nb][r] * inv0[r]);
      O[idx + (size_t)16 * 2048] = (__bf16)(acc1[nb][r] * inv1[r]);
    }
}

// ---------------- launch ----------------
extern "C" void kernel_launch(void* const* d_in, const int* in_sizes, int n_in,
                              void* d_out, int out_size, void* d_ws, size_t ws_size,
                              hipStream_t stream) {
  const float* x    = (const float*)d_in[0];
  const float* Wq   = (const float*)d_in[1];
  const float* Wk   = (const float*)d_in[2];
  const float* Wv   = (const float*)d_in[3];
  const float* Wo   = (const float*)d_in[4];
  const float* qw   = (const float*)d_in[5];
  const float* kw   = (const float*)d_in[6];
  const float* cosT = (const float*)d_in[7];
  const float* sinT = (const float*)d_in[8];
  const unsigned char* pad = (const unsigned char*)d_in[9];
  const int* win    = (const int*)d_in[10];

  char* ws = (char*)d_ws;
  __bf16* xb    = (__bf16*)(ws + 0);          // 4096x2048 bf16        (16 MB)
  __bf16* Wqkvt = (__bf16*)(ws + 16777216);   // 3072x2048 bf16        (12 MB)
  __bf16* Wot   = (__bf16*)(ws + 29360128);   // 2048x2048 bf16        (8 MB)
  __bf16* Qb    = (__bf16*)(ws + 37748736);   // [2][16][2048][128]    (16 MB)
  __bf16* Kb    = (__bf16*)(ws + 54525952);   // [2][4][2048][128]     (4 MB)
  __bf16* Vt    = (__bf16*)(ws + 58720256);   // [2][4][128][2048]     (4 MB)
  __bf16* Ob    = (__bf16*)(ws + 62914560);   // 4096x2048 bf16        (16 MB)
  unsigned char* pad64 = (unsigned char*)(ws + 79691776);  // [2][32]

  static int qkv_attr = (int)hipFuncSetAttribute(
      (const void*)gemm_qkv256, hipFuncAttributeMaxDynamicSharedMemorySize, 131072);
  (void)qkv_attr;

  prep<<<dim3(288, 64, 1), dim3(32, 8, 1), 0, stream>>>(
      Wq, Wk, Wv, Wo, (const float4*)x, (const unsigned long long*)pad,
      Wqkvt, Wot, (bf16x4*)xb, pad64);

  gemm_qkv256<<<dim3(192, 1, 1), 512, 131072, stream>>>(xb, Wqkvt, Qb, Kb, Vt);

  norm_rope<<<20480, 256, 0, stream>>>(Qb, Kb, qw, kw, cosT, sinT);

  attn<<<dim3(64, 4, 2), 256, 0, stream>>>(Qb, Kb, Vt, pad, pad64, win, Ob);

  gemm_bt<<<dim3(16, 32, 1), 256, 0, stream>>>(Ob, Wot, (float*)d_out, 4096, 2048, 2048);
}

// Round 3
// 320.455 us; speedup vs baseline: 1.0065x; 1.0065x over previous
//
#include <hip/hip_runtime.h>

typedef __attribute__((ext_vector_type(4))) float f32x4;
typedef __attribute__((ext_vector_type(8))) __bf16 bf16x8;
typedef __attribute__((ext_vector_type(4))) __bf16 bf16x4;

__device__ __forceinline__ void gload_lds16(const __bf16* g, __bf16* l) {
  __builtin_amdgcn_global_load_lds(
      (const __attribute__((address_space(1))) unsigned int*)(g),
      (__attribute__((address_space(3))) unsigned int*)(l), 16, 0, 0);
}

// ---------------- prep: weight transposes + x convert + pad_or, one launch --------
__global__ __launch_bounds__(256) void prep(
    const float* __restrict__ Wq, const float* __restrict__ Wk,
    const float* __restrict__ Wv, const float* __restrict__ Wo,
    const float4* __restrict__ x, const unsigned long long* __restrict__ pad,
    __bf16* __restrict__ Wqkvt, __bf16* __restrict__ Wot,
    bf16x4* __restrict__ xb, unsigned char* __restrict__ pad64) {
  const int bx = blockIdx.x, by = blockIdx.y;
  const int tx = threadIdx.x, ty = threadIdx.y;
  const int tid = ty * 32 + tx;
  if (bx >= 160) {
    int i = ((bx - 160) * 64 + by) * 256 + tid;
    float4 v = x[i];
    bf16x4 o = {(__bf16)v.x, (__bf16)v.y, (__bf16)v.z, (__bf16)v.w};
    xb[i] = o;
    return;
  }
  if (bx == 0 && by == 0 && tid < 64) {
    unsigned long long acc = 0;
#pragma unroll
    for (int i = 0; i < 8; ++i) acc |= pad[tid * 8 + i];
    pad64[tid] = (acc != 0) ? 1 : 0;
  }
  __shared__ float t[32][33];
  const float* src; __bf16* dst; int ss, c0;
  if (bx < 64)      { src = Wq; dst = Wqkvt;                       ss = 2048; c0 = bx * 32; }
  else if (bx < 80) { src = Wk; dst = Wqkvt + (size_t)2048 * 2048; ss = 512;  c0 = (bx - 64) * 32; }
  else if (bx < 96) { src = Wv; dst = Wqkvt + (size_t)2560 * 2048; ss = 512;  c0 = (bx - 80) * 32; }
  else              { src = Wo; dst = Wot;                         ss = 2048; c0 = (bx - 96) * 32; }
  const int r0 = by * 32;
#pragma unroll
  for (int i = ty; i < 32; i += 8)
    t[i][tx] = src[(size_t)(r0 + i) * ss + c0 + tx];
  __syncthreads();
#pragma unroll
  for (int i = ty; i < 32; i += 8)
    dst[(size_t)(c0 + i) * 2048 + r0 + tx] = (__bf16)t[tx][i];
}

// ---------------- QKV GEMM: 128x192 tile, BK=64, 512 blocks = 2 blocks/CU ----------
// C = xb[4096][2048] * Wqkvt[3072][2048]^T. Grid 512 (32 m x 16 n, XCD-bijective
// swizzle), 512 threads = 8 waves (2M x 4N), per-wave output 64x48.
// LDS 80 KiB dynamic: 2 x (A 128x64 + B 192x64) bf16 -> 2 blocks/CU (160K exact),
// 16 waves/CU: co-resident block hides the other's stage/vmcnt/barrier drain.
// Counted vmcnt (5 loads/tile in flight for tile t+1), stage t+2 after end barrier.
// T2 granule swizzle g^=(row&7): linear LDS dest, inverse-swizzled global source,
// swizzled ds_read (verified: 33K conflicts in R1 vs 6.4M unswizzled).
__device__ __forceinline__ void stage5(const __bf16* aS, const __bf16* bS,
                                       __bf16* Ab, __bf16* Bb, int wb8, size_t kt) {
#pragma unroll
  for (int l = 0; l < 2; ++l)
    gload_lds16(aS + (size_t)l * 131072 + kt, Ab + l * 4096 + wb8);
#pragma unroll
  for (int l = 0; l < 3; ++l)
    gload_lds16(bS + (size_t)l * 131072 + kt, Bb + l * 4096 + wb8);
}

__global__ __launch_bounds__(512, 4) void gemm_qkv192(
    const __bf16* __restrict__ A, const __bf16* __restrict__ Bt,
    __bf16* __restrict__ Qb, __bf16* __restrict__ Kb, __bf16* __restrict__ Vt) {
  extern __shared__ __bf16 smem[];
  const int K = 2048;
  const int tid = threadIdx.x;
  const int lane = tid & 63, w = tid >> 6;
  const int c15 = lane & 15, quad = lane >> 4;
  const int wm = w >> 2, wn = w & 3;
  const int id = blockIdx.x;
  const int swz = (id & 7) * 64 + (id >> 3);   // bijective: 512 = 8*64
  const int m0 = (swz >> 4) * 128, n0 = (swz & 15) * 192;

  const int srow = tid >> 3;
  const int scol = ((tid & 7) ^ (srow & 7)) * 8;
  const __bf16* aSrc = A + (size_t)(m0 + srow) * K + scol;
  const __bf16* bSrc = Bt + (size_t)(n0 + srow) * K + scol;
  const int wb8 = (tid & 448) * 8;   // wave-uniform LDS base (elems)
  // buffers (elems): A0 @0 (8192), B0 @8192 (12288), A1 @20480, B1 @28672
  f32x4 acc[4][3] = {};

  stage5(aSrc, bSrc, smem, smem + 8192, wb8, 0);
  stage5(aSrc, bSrc, smem + 20480, smem + 28672, wb8, 64);

  for (int t = 0; t < 32; ++t) {
    __bf16* Ab = smem + (t & 1) * 20480;
    __bf16* Bb = Ab + 8192;
    if (t < 31) asm volatile("s_waitcnt vmcnt(5)" ::: "memory");
    else        asm volatile("s_waitcnt vmcnt(0)" ::: "memory");
    __builtin_amdgcn_s_barrier();
    __builtin_amdgcn_sched_barrier(0);

    bf16x8 bF[3][2];
#pragma unroll
    for (int j = 0; j < 3; ++j) {
      int RB = wn * 48 + j * 16 + c15;
#pragma unroll
      for (int h = 0; h < 2; ++h)
        bF[j][h] = *(const bf16x8*)(Bb + RB * 64 + (((h * 4 + quad) ^ (RB & 7)) * 8));
    }
    __builtin_amdgcn_s_setprio(1);
#pragma unroll
    for (int i = 0; i < 4; ++i) {
      int RA = wm * 64 + i * 16 + c15;
      bf16x8 a0 = *(const bf16x8*)(Ab + RA * 64 + ((quad ^ (RA & 7)) * 8));
      bf16x8 a1 = *(const bf16x8*)(Ab + RA * 64 + (((4 + quad) ^ (RA & 7)) * 8));
#pragma unroll
      for (int j = 0; j < 3; ++j) {
        acc[i][j] = __builtin_amdgcn_mfma_f32_16x16x32_bf16(a0, bF[j][0], acc[i][j], 0, 0, 0);
        acc[i][j] = __builtin_amdgcn_mfma_f32_16x16x32_bf16(a1, bF[j][1], acc[i][j], 0, 0, 0);
      }
    }
    __builtin_amdgcn_s_setprio(0);
    __builtin_amdgcn_sched_barrier(0);
    asm volatile("s_waitcnt lgkmcnt(0)" ::: "memory");
    __builtin_amdgcn_s_barrier();
    __builtin_amdgcn_sched_barrier(0);
    if (t < 30) stage5(aSrc, bSrc, Ab, Bb, wb8, (size_t)(t + 2) * 64);
  }

  // ---- epilogue: per-wave 10KB LDS chunk; waves independent (no cross-wave sync).
  // Unified stage [s(64)][stride 56], cols 0..47. Routing per 8-col granule:
  // c<2048 Q rows-out, 2048<=c<2560 K rows-out, c>=2560 V column-gather (transpose).
  const int b = m0 >> 11;
  const int s0 = m0 & 2047;
  const int colbase = n0 + wn * 48;
  __bf16* st = smem + w * 5120;

#pragma unroll
  for (int i = 0; i < 4; ++i)
#pragma unroll
    for (int j = 0; j < 3; ++j)
#pragma unroll
      for (int r = 0; r < 4; ++r)
        st[(i * 16 + quad * 4 + r) * 56 + j * 16 + c15] = (__bf16)acc[i][j][r];
  __syncthreads();

  // Q/K granules: coalesced 16B row chunks
  {
    const int g = lane & 7, sl = lane >> 3;
    int c = colbase + g * 8;
    if (g < 6 && c < 2560) {
      __bf16* hp = (c < 2048)
          ? Qb + (((size_t)b * 16 + (c >> 7)) * 2048 + s0 + wm * 64) * 128 + (c & 127)
          : Kb + (((size_t)b * 4 + ((c - 2048) >> 7)) * 2048 + s0 + wm * 64) * 128 + (c & 127);
#pragma unroll
      for (int it = 0; it < 8; ++it) {
        int s = it * 8 + sl;
        *(bf16x8*)(hp + (size_t)s * 128) = *(const bf16x8*)(st + s * 56 + g * 8);
      }
    }
  }
  // V granules: transpose via column gather, 16B contiguous-in-s writes
#pragma unroll
  for (int it = 0; it < 6; ++it) {
    int lc = it * 8 + (lane >> 3);
    int c = colbase + lc;
    if (c >= 2560) {
      int sc = lane & 7;
      bf16x8 o;
#pragma unroll
      for (int rr = 0; rr < 8; ++rr) o[rr] = st[(sc * 8 + rr) * 56 + lc];
      __bf16* vp = Vt + (((size_t)b * 4 + ((c - 2560) >> 7)) * 128 + ((c - 2560) & 127)) * 2048
                   + s0 + wm * 64 + sc * 8;
      *(bf16x8*)vp = o;
    }
  }
}

// ---------------- RMSNorm + RoPE, in-place on bf16 Q/K ----------------
__global__ __launch_bounds__(256) void norm_rope(
    __bf16* __restrict__ Qb, __bf16* __restrict__ Kb,
    const float* __restrict__ qw, const float* __restrict__ kw,
    const float* __restrict__ cosT, const float* __restrict__ sinT) {
  const int tid = threadIdx.x, w = tid >> 6, lane = tid & 63;
  const int v = blockIdx.x * 4 + w;
  const bool isQ = v < 65536;
  __bf16* base = isQ ? Qb + (size_t)v * 128 : Kb + (size_t)(v - 65536) * 128;
  const int s = v & 2047;
  float x1 = (float)base[lane], x2 = (float)base[lane + 64];
  float ss = x1 * x1 + x2 * x2;
#pragma unroll
  for (int d = 32; d; d >>= 1) ss += __shfl_xor(ss, d);
  float rn = rsqrtf(ss * (1.0f / 128.0f) + 1e-8f);
  const float* wt = isQ ? qw : kw;
  float n1 = x1 * rn * (1.0f + wt[lane]);
  float n2 = x2 * rn * (1.0f + wt[lane + 64]);
  float c1 = cosT[s * 128 + lane], c2 = cosT[s * 128 + 64 + lane];
  float s1 = sinT[s * 128 + lane], s2 = sinT[s * 128 + 64 + lane];
  const float QSC = 0.08838834764831845f * 1.4426950408889634f;  // scale * log2(e)
  float post = isQ ? QSC : 1.0f;
  base[lane]      = (__bf16)((n1 * c1 - n2 * s1) * post);
  base[lane + 64] = (__bf16)((n2 * c2 + n1 * s2) * post);
}

// ---------------- m97-style bf16 GEMM (output projection) ----------------
__global__ __launch_bounds__(256) void gemm_bt(const __bf16* __restrict__ A,
                                               const __bf16* __restrict__ Bt,
                                               float* __restrict__ C,
                                               int M, int N, int K) {
  __shared__ __align__(16) __bf16 As[128 * 32];
  __shared__ __align__(16) __bf16 Bs[128 * 32];
  const int tid = threadIdx.x;
  const int lane = tid & 63;
  const int c15 = lane & 15, quad = lane >> 4;
  const int wm = ((tid >> 6) & 1) * 64;
  const int wn = (tid >> 7) * 64;
  const int m0 = blockIdx.y * 128, n0 = blockIdx.x * 128;
  const int wbase = tid & 192;

  f32x4 acc[4][4] = {};

  const int row0 = tid >> 2, cc0 = (tid & 3) * 8;
  const int row1 = (tid + 256) >> 2;
  const __bf16* a0 = A + (size_t)(m0 + row0) * K + cc0;
  const __bf16* a1 = A + (size_t)(m0 + row1) * K + cc0;
  const __bf16* b0 = Bt + (size_t)(n0 + row0) * K + cc0;
  const __bf16* b1 = Bt + (size_t)(n0 + row1) * K + cc0;
  __bf16* lA0 = As + (size_t)wbase * 8;
  __bf16* lA1 = As + (size_t)(256 + wbase) * 8;
  __bf16* lB0 = Bs + (size_t)wbase * 8;
  __bf16* lB1 = Bs + (size_t)(256 + wbase) * 8;

  for (int k0 = 0; k0 < K; k0 += 32) {
    gload_lds16(a0 + k0, lA0);
    gload_lds16(a1 + k0, lA1);
    gload_lds16(b0 + k0, lB0);
    gload_lds16(b1 + k0, lB1);
    __syncthreads();
    bf16x8 af[4], bfr[4];
#pragma unroll
    for (int i = 0; i < 4; ++i) {
      af[i]  = *(const bf16x8*)(As + (wm + i * 16 + c15) * 32 + quad * 8);
      bfr[i] = *(const bf16x8*)(Bs + (wn + i * 16 + c15) * 32 + quad * 8);
    }
#pragma unroll
    for (int i = 0; i < 4; ++i)
#pragma unroll
      for (int j = 0; j < 4; ++j)
        acc[i][j] = __builtin_amdgcn_mfma_f32_16x16x32_bf16(af[i], bfr[j], acc[i][j], 0, 0, 0);
    __syncthreads();
  }

#pragma unroll
  for (int i = 0; i < 4; ++i) {
    int r0 = m0 + wm + i * 16 + quad * 4;
#pragma unroll
    for (int j = 0; j < 4; ++j) {
      int cc = n0 + wn + j * 16 + c15;
#pragma unroll
      for (int r = 0; r < 4; ++r)
        C[(size_t)(r0 + r) * N + cc] = acc[i][j][r];
    }
  }
}

// ---------------- Flash attention v4: 32 q-rows per wave ----------------
__global__ __launch_bounds__(256) void attn(
    const __bf16* __restrict__ Qb, const __bf16* __restrict__ Kb,
    const __bf16* __restrict__ Vt, const unsigned char* __restrict__ pad,
    const unsigned char* __restrict__ pad64, const int* __restrict__ winp,
    __bf16* __restrict__ O) {
  const int S = 2048;
  __shared__ __align__(16) __bf16 Ks[64 * 128];
  __shared__ __align__(16) __bf16 Vs[128 * 64];
  __shared__ __align__(16) __bf16 Ps[4 * 32 * 72];
  const int tid = threadIdx.x, w = tid >> 6, lane = tid & 63;
  const int c15 = lane & 15, quad = lane >> 4;
  const int b = blockIdx.z;
  const int bx = (b == 0) ? blockIdx.x : (gridDim.x - 1 - blockIdx.x);
  const int q0 = ((int)gridDim.x - 1 - bx) * 32;
  const int kv = blockIdx.y;
  const int h = kv * 4 + w;
  const int W = *winp;
  const unsigned char* padb = pad + (size_t)b * S;
  const unsigned char* pad64b = pad64 + b * 32;
  const __bf16* Qh = Qb + (((size_t)b * 16 + h) * S) * 128;
  const __bf16* Kh = Kb + (((size_t)b * 4 + kv) * S) * 128;
  const __bf16* Vh = Vt + (((size_t)b * 4 + kv) * 128) * (size_t)S;
  __bf16* Pw = Ps + w * 32 * 72;

  bf16x8 qf0[4], qf1[4];
#pragma unroll
  for (int c = 0; c < 4; ++c) {
    qf0[c] = *(const bf16x8*)(Qh + (size_t)(q0 + c15) * 128 + c * 32 + quad * 8);
    qf1[c] = *(const bf16x8*)(Qh + (size_t)(q0 + 16 + c15) * 128 + c * 32 + quad * 8);
  }

  f32x4 acc0[8] = {}, acc1[8] = {};
  float lsum0[4] = {0.f, 0.f, 0.f, 0.f};
  float lsum1[4] = {0.f, 0.f, 0.f, 0.f};

  const int krow_i = lane >> 4, kch = lane & 15;
  const int vrow_i = lane >> 3, vch = lane & 7;

  int kb0 = q0 - W; if (kb0 < 0) kb0 = 0; kb0 &= ~63;

  for (int kb = kb0; kb <= q0 + 31; kb += 64) {
    __syncthreads();
#pragma unroll
    for (int i = 0; i < 4; ++i) {
      int row = w * 16 + i * 4 + krow_i;
      gload_lds16(Kh + (size_t)(kb + row) * 128 + ((kch ^ (row & 15)) * 8),
                  Ks + (w * 16 + i * 4) * 128);
    }
#pragma unroll
    for (int i = 0; i < 4; ++i) {
      int row = w * 32 + i * 8 + vrow_i;
      gload_lds16(Vh + (size_t)row * S + kb + ((vch ^ (row & 7)) * 8),
                  Vs + (w * 32 + i * 8) * 64);
    }
    __syncthreads();

    f32x4 sf0[4], sf1[4];
#pragma unroll
    for (int nb = 0; nb < 4; ++nb) {
      f32x4 ca = {}, cb = {};
#pragma unroll
      for (int c = 0; c < 4; ++c) {
        bf16x8 kf = *(const bf16x8*)(Ks + (nb * 16 + c15) * 128 + (((c * 4 + quad) ^ c15) * 8));
        ca = __builtin_amdgcn_mfma_f32_16x16x32_bf16(qf0[c], kf, ca, 0, 0, 0);
        cb = __builtin_amdgcn_mfma_f32_16x16x32_bf16(qf1[c], kf, cb, 0, 0, 0);
      }
      sf0[nb] = ca; sf1[nb] = cb;
    }

    const bool fast = (kb + 63 <= q0) && (q0 + 31 - kb <= W) && (pad64b[kb >> 6] == 0);
    if (fast) {
#pragma unroll
      for (int r = 0; r < 4; ++r) {
        float a0 = exp2f(sf0[0][r]), a1 = exp2f(sf0[1][r]);
        float a2 = exp2f(sf0[2][r]), a3 = exp2f(sf0[3][r]);
        lsum0[r] += (a0 + a1) + (a2 + a3);
        int pr = (quad * 4 + r) * 72 + c15;
        Pw[pr] = (__bf16)a0; Pw[pr + 16] = (__bf16)a1;
        Pw[pr + 32] = (__bf16)a2; Pw[pr + 48] = (__bf16)a3;
        float b0 = exp2f(sf1[0][r]), b1 = exp2f(sf1[1][r]);
        float b2 = exp2f(sf1[2][r]), b3 = exp2f(sf1[3][r]);
        lsum1[r] += (b0 + b1) + (b2 + b3);
        int qr = pr + 16 * 72;
        Pw[qr] = (__bf16)b0; Pw[qr + 16] = (__bf16)b1;
        Pw[qr + 32] = (__bf16)b2; Pw[qr + 48] = (__bf16)b3;
      }
    } else {
#pragma unroll
      for (int r = 0; r < 4; ++r) {
        const int qi0 = q0 + quad * 4 + r;
        const int qi1 = qi0 + 16;
        float p0[4], p1[4];
#pragma unroll
        for (int nb = 0; nb < 4; ++nb) {
          int ki = kb + nb * 16 + c15;
          bool okp = (padb[ki] == 0);
          bool ok0 = (ki <= qi0) && ((qi0 - ki) <= W) && okp;
          bool ok1 = (ki <= qi1) && ((qi1 - ki) <= W) && okp;
          float e0 = exp2f(sf0[nb][r]);
          float e1 = exp2f(sf1[nb][r]);
          p0[nb] = ok0 ? e0 : 0.0f;
          p1[nb] = ok1 ? e1 : 0.0f;
        }
        lsum0[r] += (p0[0] + p0[1]) + (p0[2] + p0[3]);
        lsum1[r] += (p1[0] + p1[1]) + (p1[2] + p1[3]);
        int pr = (quad * 4 + r) * 72 + c15;
        Pw[pr] = (__bf16)p0[0]; Pw[pr + 16] = (__bf16)p0[1];
        Pw[pr + 32] = (__bf16)p0[2]; Pw[pr + 48] = (__bf16)p0[3];
        int qr = pr + 16 * 72;
        Pw[qr] = (__bf16)p1[0]; Pw[qr + 16] = (__bf16)p1[1];
        Pw[qr + 32] = (__bf16)p1[2]; Pw[qr + 48] = (__bf16)p1[3];
      }
    }

    bf16x8 pf00 = *(const bf16x8*)(Pw + c15 * 72 + quad * 8);
    bf16x8 pf01 = *(const bf16x8*)(Pw + c15 * 72 + 32 + quad * 8);
    bf16x8 pf10 = *(const bf16x8*)(Pw + (16 + c15) * 72 + quad * 8);
    bf16x8 pf11 = *(const bf16x8*)(Pw + (16 + c15) * 72 + 32 + quad * 8);
#pragma unroll
    for (int nb = 0; nb < 8; ++nb) {
      int row = nb * 16 + c15;
      bf16x8 vf0 = *(const bf16x8*)(Vs + row * 64 + ((quad ^ (c15 & 7)) * 8));
      bf16x8 vf1 = *(const bf16x8*)(Vs + row * 64 + (((4 + quad) ^ (c15 & 7)) * 8));
      acc0[nb] = __builtin_amdgcn_mfma_f32_16x16x32_bf16(pf00, vf0, acc0[nb], 0, 0, 0);
      acc0[nb] = __builtin_amdgcn_mfma_f32_16x16x32_bf16(pf01, vf1, acc0[nb], 0, 0, 0);
      acc1[nb] = __builtin_amdgcn_mfma_f32_16x16x32_bf16(pf10, vf0, acc1[nb], 0, 0, 0);
      acc1[nb] = __builtin_amdgcn_mfma_f32_16x16x32_bf16(pf11, vf1, acc1[nb], 0, 0, 0);
    }
  }

#pragma unroll
  for (int r = 0; r < 4; ++r) {
    lsum0[r] += __shfl_xor(lsum0[r], 1);
    lsum0[r] += __shfl_xor(lsum0[r], 2);
    lsum0[r] += __shfl_xor(lsum0[r], 4);
    lsum0[r] += __shfl_xor(lsum0[r], 8);
    lsum1[r] += __shfl_xor(lsum1[r], 1);
    lsum1[r] += __shfl_xor(lsum1[r], 2);
    lsum1[r] += __shfl_xor(lsum1[r], 4);
    lsum1[r] += __shfl_xor(lsum1[r], 8);
  }
  float inv0[4], inv1[4];
#pragma unroll
  for (int r = 0; r < 4; ++r) { inv0[r] = 1.0f / lsum0[r]; inv1[r] = 1.0f / lsum1[r]; }
#pragma unroll
  for (int nb = 0; nb < 8; ++nb)
#pragma unroll
    for (int r = 0; r < 4; ++r) {
      size_t idx = ((size_t)b * S + q0 + quad * 4 + r) * 2048 + h * 128 + nb * 16 + c15;
      O[idx] = (__bf16)(acc0[nb][r] * inv0[r]);
      O[idx + (size_t)16 * 2048] = (__bf16)(acc1[nb][r] * inv1[r]);
    }
}

// ---------------- launch ----------------
extern "C" void kernel_launch(void* const* d_in, const int* in_sizes, int n_in,
                              void* d_out, int out_size, void* d_ws, size_t ws_size,
                              hipStream_t stream) {
  const float* x    = (const float*)d_in[0];
  const float* Wq   = (const float*)d_in[1];
  const float* Wk   = (const float*)d_in[2];
  const float* Wv   = (const float*)d_in[3];
  const float* Wo   = (const float*)d_in[4];
  const float* qw   = (const float*)d_in[5];
  const float* kw   = (const float*)d_in[6];
  const float* cosT = (const float*)d_in[7];
  const float* sinT = (const float*)d_in[8];
  const unsigned char* pad = (const unsigned char*)d_in[9];
  const int* win    = (const int*)d_in[10];

  char* ws = (char*)d_ws;
  __bf16* xb    = (__bf16*)(ws + 0);          // 4096x2048 bf16        (16 MB)
  __bf16* Wqkvt = (__bf16*)(ws + 16777216);   // 3072x2048 bf16        (12 MB)
  __bf16* Wot   = (__bf16*)(ws + 29360128);   // 2048x2048 bf16        (8 MB)
  __bf16* Qb    = (__bf16*)(ws + 37748736);   // [2][16][2048][128]    (16 MB)
  __bf16* Kb    = (__bf16*)(ws + 54525952);   // [2][4][2048][128]     (4 MB)
  __bf16* Vt    = (__bf16*)(ws + 58720256);   // [2][4][128][2048]     (4 MB)
  __bf16* Ob    = (__bf16*)(ws + 62914560);   // 4096x2048 bf16        (16 MB)
  unsigned char* pad64 = (unsigned char*)(ws + 79691776);  // [2][32]

  static int qkv_attr = (int)hipFuncSetAttribute(
      (const void*)gemm_qkv192, hipFuncAttributeMaxDynamicSharedMemorySize, 81920);
  (void)qkv_attr;

  prep<<<dim3(288, 64, 1), dim3(32, 8, 1), 0, stream>>>(
      Wq, Wk, Wv, Wo, (const float4*)x, (const unsigned long long*)pad,
      Wqkvt, Wot, (bf16x4*)xb, pad64);

  gemm_qkv192<<<dim3(512, 1, 1), 512, 81920, stream>>>(xb, Wqkvt, Qb, Kb, Vt);

  norm_rope<<<20480, 256, 0, stream>>>(Qb, Kb, qw, kw, cosT, sinT);

  attn<<<dim3(64, 4, 2), 256, 0, stream>>>(Qb, Kb, Vt, pad, pad64, win, Ob);

  gemm_bt<<<dim3(16, 32, 1), 256, 0, stream>>>(Ob, Wot, (float*)d_out, 4096, 2048, 2048);
}

// Round 5
// 305.682 us; speedup vs baseline: 1.0552x; 1.0483x over previous
//
#include <hip/hip_runtime.h>

typedef __attribute__((ext_vector_type(4))) float f32x4;
typedef __attribute__((ext_vector_type(8))) __bf16 bf16x8;
typedef __attribute__((ext_vector_type(4))) __bf16 bf16x4;

__device__ __forceinline__ void gload_lds16(const __bf16* g, __bf16* l) {
  __builtin_amdgcn_global_load_lds(
      (const __attribute__((address_space(1))) unsigned int*)(g),
      (__attribute__((address_space(3))) unsigned int*)(l), 16, 0, 0);
}

// ---------------- prep: weight transposes + x convert + pad_or, one launch --------
__global__ __launch_bounds__(256) void prep(
    const float* __restrict__ Wq, const float* __restrict__ Wk,
    const float* __restrict__ Wv, const float* __restrict__ Wo,
    const float4* __restrict__ x, const unsigned long long* __restrict__ pad,
    __bf16* __restrict__ Wqkvt, __bf16* __restrict__ Wot,
    bf16x4* __restrict__ xb, unsigned char* __restrict__ pad64) {
  const int bx = blockIdx.x, by = blockIdx.y;
  const int tx = threadIdx.x, ty = threadIdx.y;
  const int tid = ty * 32 + tx;
  if (bx >= 160) {
    int i = ((bx - 160) * 64 + by) * 256 + tid;
    float4 v = x[i];
    bf16x4 o = {(__bf16)v.x, (__bf16)v.y, (__bf16)v.z, (__bf16)v.w};
    xb[i] = o;
    return;
  }
  if (bx == 0 && by == 0 && tid < 64) {
    unsigned long long acc = 0;
#pragma unroll
    for (int i = 0; i < 8; ++i) acc |= pad[tid * 8 + i];
    pad64[tid] = (acc != 0) ? 1 : 0;
  }
  __shared__ float t[32][33];
  const float* src; __bf16* dst; int ss, c0;
  if (bx < 64)      { src = Wq; dst = Wqkvt;                       ss = 2048; c0 = bx * 32; }
  else if (bx < 80) { src = Wk; dst = Wqkvt + (size_t)2048 * 2048; ss = 512;  c0 = (bx - 64) * 32; }
  else if (bx < 96) { src = Wv; dst = Wqkvt + (size_t)2560 * 2048; ss = 512;  c0 = (bx - 80) * 32; }
  else              { src = Wo; dst = Wot;                         ss = 2048; c0 = (bx - 96) * 32; }
  const int r0 = by * 32;
#pragma unroll
  for (int i = ty; i < 32; i += 8)
    t[i][tx] = src[(size_t)(r0 + i) * ss + c0 + tx];
  __syncthreads();
#pragma unroll
  for (int i = ty; i < 32; i += 8)
    dst[(size_t)(c0 + i) * 2048 + r0 + tx] = (__bf16)t[tx][i];
}

// ---------------- QKV GEMM: 128x192 tile, BK=64, safe 2-phase double-buffer -------
// C = xb[4096][2048] * Wqkvt[3072][2048]^T. Grid 512 (32m x 16n, XCD-bijective),
// 512 threads = 8 waves (2M x 4N), per-wave 64x48. LDS 80 KiB dyn -> 2 blocks/CU.
// SAFE schedule (R3's raw-barrier counted-vmcnt version was non-deterministic):
//   stage(buf[cur^1], t+1) issued BEFORE compute; compute from buf[cur];
//   __syncthreads() (full vmcnt/lgkmcnt drain + barrier) once per K-tile.
// A wave only stages the buffer nobody reads this iter; the end-of-iter sync both
// drains all reads before the next overwrite and lands tile t+1 before any read.
// T2 granule swizzle g^=(row&7): linear LDS dest, inverse-swizzled global source,
// swizzled ds_read (verified: 33K conflicts vs 6.4M unswizzled).
__device__ __forceinline__ void stage5(const __bf16* aS, const __bf16* bS,
                                       __bf16* Ab, __bf16* Bb, int wb8, size_t kt) {
#pragma unroll
  for (int l = 0; l < 2; ++l)
    gload_lds16(aS + (size_t)l * 131072 + kt, Ab + l * 4096 + wb8);
#pragma unroll
  for (int l = 0; l < 3; ++l)
    gload_lds16(bS + (size_t)l * 131072 + kt, Bb + l * 4096 + wb8);
}

__global__ __launch_bounds__(512, 4) void gemm_qkv192(
    const __bf16* __restrict__ A, const __bf16* __restrict__ Bt,
    __bf16* __restrict__ Qb, __bf16* __restrict__ Kb, __bf16* __restrict__ Vt) {
  extern __shared__ __bf16 smem[];
  const int K = 2048;
  const int tid = threadIdx.x;
  const int lane = tid & 63, w = tid >> 6;
  const int c15 = lane & 15, quad = lane >> 4;
  const int wm = w >> 2, wn = w & 3;
  const int id = blockIdx.x;
  const int swz = (id & 7) * 64 + (id >> 3);   // bijective: 512 = 8*64
  const int m0 = (swz >> 4) * 128, n0 = (swz & 15) * 192;

  const int srow = tid >> 3;
  const int scol = ((tid & 7) ^ (srow & 7)) * 8;
  const __bf16* aSrc = A + (size_t)(m0 + srow) * K + scol;
  const __bf16* bSrc = Bt + (size_t)(n0 + srow) * K + scol;
  const int wb8 = (tid & 448) * 8;   // wave-uniform LDS base (elems)
  // buffers (elems): A0 @0 (8192), B0 @8192 (12288), A1 @20480, B1 @28672
  f32x4 acc[4][3] = {};

  stage5(aSrc, bSrc, smem, smem + 8192, wb8, 0);
  __syncthreads();

  for (int t = 0; t < 32; ++t) {
    __bf16* Ab = smem + (t & 1) * 20480;
    __bf16* Bb = Ab + 8192;
    if (t < 31) {
      __bf16* An = smem + ((t + 1) & 1) * 20480;
      stage5(aSrc, bSrc, An, An + 8192, wb8, (size_t)(t + 1) * 64);
    }
    bf16x8 bF[3][2];
#pragma unroll
    for (int j = 0; j < 3; ++j) {
      int RB = wn * 48 + j * 16 + c15;
#pragma unroll
      for (int h = 0; h < 2; ++h)
        bF[j][h] = *(const bf16x8*)(Bb + RB * 64 + (((h * 4 + quad) ^ (RB & 7)) * 8));
    }
    __builtin_amdgcn_s_setprio(1);
#pragma unroll
    for (int i = 0; i < 4; ++i) {
      int RA = wm * 64 + i * 16 + c15;
      bf16x8 a0 = *(const bf16x8*)(Ab + RA * 64 + ((quad ^ (RA & 7)) * 8));
      bf16x8 a1 = *(const bf16x8*)(Ab + RA * 64 + (((4 + quad) ^ (RA & 7)) * 8));
#pragma unroll
      for (int j = 0; j < 3; ++j) {
        acc[i][j] = __builtin_amdgcn_mfma_f32_16x16x32_bf16(a0, bF[j][0], acc[i][j], 0, 0, 0);
        acc[i][j] = __builtin_amdgcn_mfma_f32_16x16x32_bf16(a1, bF[j][1], acc[i][j], 0, 0, 0);
      }
    }
    __builtin_amdgcn_s_setprio(0);
    __syncthreads();
  }

  // ---- epilogue: per-wave 10KB LDS chunk; waves independent (no cross-wave sync).
  const int b = m0 >> 11;
  const int s0 = m0 & 2047;
  const int colbase = n0 + wn * 48;
  __bf16* st = smem + w * 5120;

#pragma unroll
  for (int i = 0; i < 4; ++i)
#pragma unroll
    for (int j = 0; j < 3; ++j)
#pragma unroll
      for (int r = 0; r < 4; ++r)
        st[(i * 16 + quad * 4 + r) * 56 + j * 16 + c15] = (__bf16)acc[i][j][r];
  __syncthreads();

  // Q/K granules: coalesced 16B row chunks
  {
    const int g = lane & 7, sl = lane >> 3;
    int c = colbase + g * 8;
    if (g < 6 && c < 2560) {
      __bf16* hp = (c < 2048)
          ? Qb + (((size_t)b * 16 + (c >> 7)) * 2048 + s0 + wm * 64) * 128 + (c & 127)
          : Kb + (((size_t)b * 4 + ((c - 2048) >> 7)) * 2048 + s0 + wm * 64) * 128 + (c & 127);
#pragma unroll
      for (int it = 0; it < 8; ++it) {
        int s = it * 8 + sl;
        *(bf16x8*)(hp + (size_t)s * 128) = *(const bf16x8*)(st + s * 56 + g * 8);
      }
    }
  }
  // V granules: transpose via column gather, 16B contiguous-in-s writes
#pragma unroll
  for (int it = 0; it < 6; ++it) {
    int lc = it * 8 + (lane >> 3);
    int c = colbase + lc;
    if (c >= 2560) {
      int sc = lane & 7;
      bf16x8 o;
#pragma unroll
      for (int rr = 0; rr < 8; ++rr) o[rr] = st[(sc * 8 + rr) * 56 + lc];
      __bf16* vp = Vt + (((size_t)b * 4 + ((c - 2560) >> 7)) * 128 + ((c - 2560) & 127)) * 2048
                   + s0 + wm * 64 + sc * 8;
      *(bf16x8*)vp = o;
    }
  }
}

// ---------------- RMSNorm + RoPE, in-place on bf16 Q/K ----------------
__global__ __launch_bounds__(256) void norm_rope(
    __bf16* __restrict__ Qb, __bf16* __restrict__ Kb,
    const float* __restrict__ qw, const float* __restrict__ kw,
    const float* __restrict__ cosT, const float* __restrict__ sinT) {
  const int tid = threadIdx.x, w = tid >> 6, lane = tid & 63;
  const int v = blockIdx.x * 4 + w;
  const bool isQ = v < 65536;
  __bf16* base = isQ ? Qb + (size_t)v * 128 : Kb + (size_t)(v - 65536) * 128;
  const int s = v & 2047;
  float x1 = (float)base[lane], x2 = (float)base[lane + 64];
  float ss = x1 * x1 + x2 * x2;
#pragma unroll
  for (int d = 32; d; d >>= 1) ss += __shfl_xor(ss, d);
  float rn = rsqrtf(ss * (1.0f / 128.0f) + 1e-8f);
  const float* wt = isQ ? qw : kw;
  float n1 = x1 * rn * (1.0f + wt[lane]);
  float n2 = x2 * rn * (1.0f + wt[lane + 64]);
  float c1 = cosT[s * 128 + lane], c2 = cosT[s * 128 + 64 + lane];
  float s1 = sinT[s * 128 + lane], s2 = sinT[s * 128 + 64 + lane];
  const float QSC = 0.08838834764831845f * 1.4426950408889634f;  // scale * log2(e)
  float post = isQ ? QSC : 1.0f;
  base[lane]      = (__bf16)((n1 * c1 - n2 * s1) * post);
  base[lane + 64] = (__bf16)((n2 * c2 + n1 * s2) * post);
}

// ---------------- output projection: 128x128 tile, BK=64, safe 2-phase dbuf -------
// C(fp32 4096x2048) = Ob[4096][2048] * Wot[2048][2048]^T. Grid 512 (32m x 16n,
// XCD-bijective), 512 threads = 8 waves (2M x 4N), per-wave 64x32, acc[4][2].
// LDS 64 KiB dyn: 2 x (A 128x64 + B 128x64) -> 2 blocks/CU. Same safe schedule as
// gemm_qkv192. Granule-XOR swizzle kills the 4.2M bank conflicts of the old
// [row][32] layout. k-order per acc unchanged -> bitwise-identical output.
__device__ __forceinline__ void stage4(const __bf16* aS, const __bf16* bS,
                                       __bf16* Ab, __bf16* Bb, int wb8, size_t kt) {
#pragma unroll
  for (int l = 0; l < 2; ++l)
    gload_lds16(aS + (size_t)l * 131072 + kt, Ab + l * 4096 + wb8);
#pragma unroll
  for (int l = 0; l < 2; ++l)
    gload_lds16(bS + (size_t)l * 131072 + kt, Bb + l * 4096 + wb8);
}

__global__ __launch_bounds__(512, 4) void gemm_bt128(
    const __bf16* __restrict__ A, const __bf16* __restrict__ Bt,
    float* __restrict__ C) {
  extern __shared__ __bf16 smem[];
  const int K = 2048, N = 2048;
  const int tid = threadIdx.x;
  const int lane = tid & 63, w = tid >> 6;
  const int c15 = lane & 15, quad = lane >> 4;
  const int wm = w >> 2, wn = w & 3;
  const int id = blockIdx.x;
  const int swz = (id & 7) * 64 + (id >> 3);   // bijective: 512 = 8*64
  const int m0 = (swz >> 4) * 128, n0 = (swz & 15) * 128;

  const int srow = tid >> 3;
  const int scol = ((tid & 7) ^ (srow & 7)) * 8;
  const __bf16* aSrc = A + (size_t)(m0 + srow) * K + scol;
  const __bf16* bSrc = Bt + (size_t)(n0 + srow) * K + scol;
  const int wb8 = (tid & 448) * 8;

  f32x4 acc[4][2] = {};

  stage4(aSrc, bSrc, smem, smem + 8192, wb8, 0);
  __syncthreads();

  for (int t = 0; t < 32; ++t) {
    __bf16* Ab = smem + (t & 1) * 16384;
    __bf16* Bb = Ab + 8192;
    if (t < 31) {
      __bf16* An = smem + ((t + 1) & 1) * 16384;
      stage4(aSrc, bSrc, An, An + 8192, wb8, (size_t)(t + 1) * 64);
    }
    bf16x8 bF[2][2];
#pragma unroll
    for (int j = 0; j < 2; ++j) {
      int RB = wn * 32 + j * 16 + c15;
#pragma unroll
      for (int h = 0; h < 2; ++h)
        bF[j][h] = *(const bf16x8*)(Bb + RB * 64 + (((h * 4 + quad) ^ (RB & 7)) * 8));
    }
    __builtin_amdgcn_s_setprio(1);
#pragma unroll
    for (int i = 0; i < 4; ++i) {
      int RA = wm * 64 + i * 16 + c15;
      bf16x8 a0 = *(const bf16x8*)(Ab + RA * 64 + ((quad ^ (RA & 7)) * 8));
      bf16x8 a1 = *(const bf16x8*)(Ab + RA * 64 + (((4 + quad) ^ (RA & 7)) * 8));
#pragma unroll
      for (int j = 0; j < 2; ++j) {
        acc[i][j] = __builtin_amdgcn_mfma_f32_16x16x32_bf16(a0, bF[j][0], acc[i][j], 0, 0, 0);
        acc[i][j] = __builtin_amdgcn_mfma_f32_16x16x32_bf16(a1, bF[j][1], acc[i][j], 0, 0, 0);
      }
    }
    __builtin_amdgcn_s_setprio(0);
    __syncthreads();
  }

#pragma unroll
  for (int i = 0; i < 4; ++i) {
    int r0 = m0 + wm * 64 + i * 16 + quad * 4;
#pragma unroll
    for (int j = 0; j < 2; ++j) {
      int cc = n0 + wn * 32 + j * 16 + c15;
#pragma unroll
      for (int r = 0; r < 4; ++r)
        C[(size_t)(r0 + r) * N + cc] = acc[i][j][r];
    }
  }
}

// ---------------- Flash attention v4: 32 q-rows per wave ----------------
__global__ __launch_bounds__(256) void attn(
    const __bf16* __restrict__ Qb, const __bf16* __restrict__ Kb,
    const __bf16* __restrict__ Vt, const unsigned char* __restrict__ pad,
    const unsigned char* __restrict__ pad64, const int* __restrict__ winp,
    __bf16* __restrict__ O) {
  const int S = 2048;
  __shared__ __align__(16) __bf16 Ks[64 * 128];
  __shared__ __align__(16) __bf16 Vs[128 * 64];
  __shared__ __align__(16) __bf16 Ps[4 * 32 * 72];
  const int tid = threadIdx.x, w = tid >> 6, lane = tid & 63;
  const int c15 = lane & 15, quad = lane >> 4;
  const int b = blockIdx.z;
  const int bx = (b == 0) ? blockIdx.x : (gridDim.x - 1 - blockIdx.x);
  const int q0 = ((int)gridDim.x - 1 - bx) * 32;
  const int kv = blockIdx.y;
  const int h = kv * 4 + w;
  const int W = *winp;
  const unsigned char* padb = pad + (size_t)b * S;
  const unsigned char* pad64b = pad64 + b * 32;
  const __bf16* Qh = Qb + (((size_t)b * 16 + h) * S) * 128;
  const __bf16* Kh = Kb + (((size_t)b * 4 + kv) * S) * 128;
  const __bf16* Vh = Vt + (((size_t)b * 4 + kv) * 128) * (size_t)S;
  __bf16* Pw = Ps + w * 32 * 72;

  bf16x8 qf0[4], qf1[4];
#pragma unroll
  for (int c = 0; c < 4; ++c) {
    qf0[c] = *(const bf16x8*)(Qh + (size_t)(q0 + c15) * 128 + c * 32 + quad * 8);
    qf1[c] = *(const bf16x8*)(Qh + (size_t)(q0 + 16 + c15) * 128 + c * 32 + quad * 8);
  }

  f32x4 acc0[8] = {}, acc1[8] = {};
  float lsum0[4] = {0.f, 0.f, 0.f, 0.f};
  float lsum1[4] = {0.f, 0.f, 0.f, 0.f};

  const int krow_i = lane >> 4, kch = lane & 15;
  const int vrow_i = lane >> 3, vch = lane & 7;

  int kb0 = q0 - W; if (kb0 < 0) kb0 = 0; kb0 &= ~63;

  for (int kb = kb0; kb <= q0 + 31; kb += 64) {
    __syncthreads();
#pragma unroll
    for (int i = 0; i < 4; ++i) {
      int row = w * 16 + i * 4 + krow_i;
      gload_lds16(Kh + (size_t)(kb + row) * 128 + ((kch ^ (row & 15)) * 8),
                  Ks + (w * 16 + i * 4) * 128);
    }
#pragma unroll
    for (int i = 0; i < 4; ++i) {
      int row = w * 32 + i * 8 + vrow_i;
      gload_lds16(Vh + (size_t)row * S + kb + ((vch ^ (row & 7)) * 8),
                  Vs + (w * 32 + i * 8) * 64);
    }
    __syncthreads();

    f32x4 sf0[4], sf1[4];
#pragma unroll
    for (int nb = 0; nb < 4; ++nb) {
      f32x4 ca = {}, cb = {};
#pragma unroll
      for (int c = 0; c < 4; ++c) {
        bf16x8 kf = *(const bf16x8*)(Ks + (nb * 16 + c15) * 128 + (((c * 4 + quad) ^ c15) * 8));
        ca = __builtin_amdgcn_mfma_f32_16x16x32_bf16(qf0[c], kf, ca, 0, 0, 0);
        cb = __builtin_amdgcn_mfma_f32_16x16x32_bf16(qf1[c], kf, cb, 0, 0, 0);
      }
      sf0[nb] = ca; sf1[nb] = cb;
    }

    const bool fast = (kb + 63 <= q0) && (q0 + 31 - kb <= W) && (pad64b[kb >> 6] == 0);
    if (fast) {
#pragma unroll
      for (int r = 0; r < 4; ++r) {
        float a0 = exp2f(sf0[0][r]), a1 = exp2f(sf0[1][r]);
        float a2 = exp2f(sf0[2][r]), a3 = exp2f(sf0[3][r]);
        lsum0[r] += (a0 + a1) + (a2 + a3);
        int pr = (quad * 4 + r) * 72 + c15;
        Pw[pr] = (__bf16)a0; Pw[pr + 16] = (__bf16)a1;
        Pw[pr + 32] = (__bf16)a2; Pw[pr + 48] = (__bf16)a3;
        float b0 = exp2f(sf1[0][r]), b1 = exp2f(sf1[1][r]);
        float b2 = exp2f(sf1[2][r]), b3 = exp2f(sf1[3][r]);
        lsum1[r] += (b0 + b1) + (b2 + b3);
        int qr = pr + 16 * 72;
        Pw[qr] = (__bf16)b0; Pw[qr + 16] = (__bf16)b1;
        Pw[qr + 32] = (__bf16)b2; Pw[qr + 48] = (__bf16)b3;
      }
    } else {
#pragma unroll
      for (int r = 0; r < 4; ++r) {
        const int qi0 = q0 + quad * 4 + r;
        const int qi1 = qi0 + 16;
        float p0[4], p1[4];
#pragma unroll
        for (int nb = 0; nb < 4; ++nb) {
          int ki = kb + nb * 16 + c15;
          bool okp = (padb[ki] == 0);
          bool ok0 = (ki <= qi0) && ((qi0 - ki) <= W) && okp;
          bool ok1 = (ki <= qi1) && ((qi1 - ki) <= W) && okp;
          float e0 = exp2f(sf0[nb][r]);
          float e1 = exp2f(sf1[nb][r]);
          p0[nb] = ok0 ? e0 : 0.0f;
          p1[nb] = ok1 ? e1 : 0.0f;
        }
        lsum0[r] += (p0[0] + p0[1]) + (p0[2] + p0[3]);
        lsum1[r] += (p1[0] + p1[1]) + (p1[2] + p1[3]);
        int pr = (quad * 4 + r) * 72 + c15;
        Pw[pr] = (__bf16)p0[0]; Pw[pr + 16] = (__bf16)p0[1];
        Pw[pr + 32] = (__bf16)p0[2]; Pw[pr + 48] = (__bf16)p0[3];
        int qr = pr + 16 * 72;
        Pw[qr] = (__bf16)p1[0]; Pw[qr + 16] = (__bf16)p1[1];
        Pw[qr + 32] = (__bf16)p1[2]; Pw[qr + 48] = (__bf16)p1[3];
      }
    }

    bf16x8 pf00 = *(const bf16x8*)(Pw + c15 * 72 + quad * 8);
    bf16x8 pf01 = *(const bf16x8*)(Pw + c15 * 72 + 32 + quad * 8);
    bf16x8 pf10 = *(const bf16x8*)(Pw + (16 + c15) * 72 + quad * 8);
    bf16x8 pf11 = *(const bf16x8*)(Pw + (16 + c15) * 72 + 32 + quad * 8);
#pragma unroll
    for (int nb = 0; nb < 8; ++nb) {
      int row = nb * 16 + c15;
      bf16x8 vf0 = *(const bf16x8*)(Vs + row * 64 + ((quad ^ (c15 & 7)) * 8));
      bf16x8 vf1 = *(const bf16x8*)(Vs + row * 64 + (((4 + quad) ^ (c15 & 7)) * 8));
      acc0[nb] = __builtin_amdgcn_mfma_f32_16x16x32_bf16(pf00, vf0, acc0[nb], 0, 0, 0);
      acc0[nb] = __builtin_amdgcn_mfma_f32_16x16x32_bf16(pf01, vf1, acc0[nb], 0, 0, 0);
      acc1[nb] = __builtin_amdgcn_mfma_f32_16x16x32_bf16(pf10, vf0, acc1[nb], 0, 0, 0);
      acc1[nb] = __builtin_amdgcn_mfma_f32_16x16x32_bf16(pf11, vf1, acc1[nb], 0, 0, 0);
    }
  }

#pragma unroll
  for (int r = 0; r < 4; ++r) {
    lsum0[r] += __shfl_xor(lsum0[r], 1);
    lsum0[r] += __shfl_xor(lsum0[r], 2);
    lsum0[r] += __shfl_xor(lsum0[r], 4);
    lsum0[r] += __shfl_xor(lsum0[r], 8);
    lsum1[r] += __shfl_xor(lsum1[r], 1);
    lsum1[r] += __shfl_xor(lsum1[r], 2);
    lsum1[r] += __shfl_xor(lsum1[r], 4);
    lsum1[r] += __shfl_xor(lsum1[r], 8);
  }
  float inv0[4], inv1[4];
#pragma unroll
  for (int r = 0; r < 4; ++r) { inv0[r] = 1.0f / lsum0[r]; inv1[r] = 1.0f / lsum1[r]; }
#pragma unroll
  for (int nb = 0; nb < 8; ++nb)
#pragma unroll
    for (int r = 0; r < 4; ++r) {
      size_t idx = ((size_t)b * S + q0 + quad * 4 + r) * 2048 + h * 128 + nb * 16 + c15;
      O[idx] = (__bf16)(acc0[nb][r] * inv0[r]);
      O[idx + (size_t)16 * 2048] = (__bf16)(acc1[nb][r] * inv1[r]);
    }
}

// ---------------- launch ----------------
extern "C" void kernel_launch(void* const* d_in, const int* in_sizes, int n_in,
                              void* d_out, int out_size, void* d_ws, size_t ws_size,
                              hipStream_t stream) {
  const float* x    = (const float*)d_in[0];
  const float* Wq   = (const float*)d_in[1];
  const float* Wk   = (const float*)d_in[2];
  const float* Wv   = (const float*)d_in[3];
  const float* Wo   = (const float*)d_in[4];
  const float* qw   = (const float*)d_in[5];
  const float* kw   = (const float*)d_in[6];
  const float* cosT = (const float*)d_in[7];
  const float* sinT = (const float*)d_in[8];
  const unsigned char* pad = (const unsigned char*)d_in[9];
  const int* win    = (const int*)d_in[10];

  char* ws = (char*)d_ws;
  __bf16* xb    = (__bf16*)(ws + 0);          // 4096x2048 bf16        (16 MB)
  __bf16* Wqkvt = (__bf16*)(ws + 16777216);   // 3072x2048 bf16        (12 MB)
  __bf16* Wot   = (__bf16*)(ws + 29360128);   // 2048x2048 bf16        (8 MB)
  __bf16* Qb    = (__bf16*)(ws + 37748736);   // [2][16][2048][128]    (16 MB)
  __bf16* Kb    = (__bf16*)(ws + 54525952);   // [2][4][2048][128]     (4 MB)
  __bf16* Vt    = (__bf16*)(ws + 58720256);   // [2][4][128][2048]     (4 MB)
  __bf16* Ob    = (__bf16*)(ws + 62914560);   // 4096x2048 bf16        (16 MB)
  unsigned char* pad64 = (unsigned char*)(ws + 79691776);  // [2][32]

  static int qkv_attr = (int)hipFuncSetAttribute(
      (const void*)gemm_qkv192, hipFuncAttributeMaxDynamicSharedMemorySize, 81920);
  (void)qkv_attr;
  static int bt_attr = (int)hipFuncSetAttribute(
      (const void*)gemm_bt128, hipFuncAttributeMaxDynamicSharedMemorySize, 65536);
  (void)bt_attr;

  prep<<<dim3(288, 64, 1), dim3(32, 8, 1), 0, stream>>>(
      Wq, Wk, Wv, Wo, (const float4*)x, (const unsigned long long*)pad,
      Wqkvt, Wot, (bf16x4*)xb, pad64);

  gemm_qkv192<<<dim3(512, 1, 1), 512, 81920, stream>>>(xb, Wqkvt, Qb, Kb, Vt);

  norm_rope<<<20480, 256, 0, stream>>>(Qb, Kb, qw, kw, cosT, sinT);

  attn<<<dim3(64, 4, 2), 256, 0, stream>>>(Qb, Kb, Vt, pad, pad64, win, Ob);

  gemm_bt128<<<dim3(512, 1, 1), 512, 65536, stream>>>(Ob, Wot, (float*)d_out);
}

// Round 6
// 298.626 us; speedup vs baseline: 1.0801x; 1.0236x over previous
//
#include <hip/hip_runtime.h>

typedef __attribute__((ext_vector_type(4))) float f32x4;
typedef __attribute__((ext_vector_type(8))) __bf16 bf16x8;
typedef __attribute__((ext_vector_type(4))) __bf16 bf16x4;

__device__ __forceinline__ void gload_lds16(const __bf16* g, __bf16* l) {
  __builtin_amdgcn_global_load_lds(
      (const __attribute__((address_space(1))) unsigned int*)(g),
      (__attribute__((address_space(3))) unsigned int*)(l), 16, 0, 0);
}

// ---------------- prep: weight transposes + x convert + pad_or, one launch --------
__global__ __launch_bounds__(256) void prep(
    const float* __restrict__ Wq, const float* __restrict__ Wk,
    const float* __restrict__ Wv, const float* __restrict__ Wo,
    const float4* __restrict__ x, const unsigned long long* __restrict__ pad,
    __bf16* __restrict__ Wqkvt, __bf16* __restrict__ Wot,
    bf16x4* __restrict__ xb, unsigned char* __restrict__ pad64) {
  const int bx = blockIdx.x, by = blockIdx.y;
  const int tx = threadIdx.x, ty = threadIdx.y;
  const int tid = ty * 32 + tx;
  if (bx >= 160) {
    int i = ((bx - 160) * 64 + by) * 256 + tid;
    float4 v = x[i];
    bf16x4 o = {(__bf16)v.x, (__bf16)v.y, (__bf16)v.z, (__bf16)v.w};
    xb[i] = o;
    return;
  }
  if (bx == 0 && by == 0 && tid < 64) {
    unsigned long long acc = 0;
#pragma unroll
    for (int i = 0; i < 8; ++i) acc |= pad[tid * 8 + i];
    pad64[tid] = (acc != 0) ? 1 : 0;
  }
  __shared__ float t[32][33];
  const float* src; __bf16* dst; int ss, c0;
  if (bx < 64)      { src = Wq; dst = Wqkvt;                       ss = 2048; c0 = bx * 32; }
  else if (bx < 80) { src = Wk; dst = Wqkvt + (size_t)2048 * 2048; ss = 512;  c0 = (bx - 64) * 32; }
  else if (bx < 96) { src = Wv; dst = Wqkvt + (size_t)2560 * 2048; ss = 512;  c0 = (bx - 80) * 32; }
  else              { src = Wo; dst = Wot;                         ss = 2048; c0 = (bx - 96) * 32; }
  const int r0 = by * 32;
#pragma unroll
  for (int i = ty; i < 32; i += 8)
    t[i][tx] = src[(size_t)(r0 + i) * ss + c0 + tx];
  __syncthreads();
#pragma unroll
  for (int i = ty; i < 32; i += 8)
    dst[(size_t)(c0 + i) * 2048 + r0 + tx] = (__bf16)t[tx][i];
}

// ---------------- QKV GEMM: 128x192 tile, BK=64, safe 2-phase double-buffer -------
__device__ __forceinline__ void stage5(const __bf16* aS, const __bf16* bS,
                                       __bf16* Ab, __bf16* Bb, int wb8, size_t kt) {
#pragma unroll
  for (int l = 0; l < 2; ++l)
    gload_lds16(aS + (size_t)l * 131072 + kt, Ab + l * 4096 + wb8);
#pragma unroll
  for (int l = 0; l < 3; ++l)
    gload_lds16(bS + (size_t)l * 131072 + kt, Bb + l * 4096 + wb8);
}

__global__ __launch_bounds__(512, 4) void gemm_qkv192(
    const __bf16* __restrict__ A, const __bf16* __restrict__ Bt,
    __bf16* __restrict__ Qb, __bf16* __restrict__ Kb, __bf16* __restrict__ Vt) {
  extern __shared__ __bf16 smem[];
  const int K = 2048;
  const int tid = threadIdx.x;
  const int lane = tid & 63, w = tid >> 6;
  const int c15 = lane & 15, quad = lane >> 4;
  const int wm = w >> 2, wn = w & 3;
  const int id = blockIdx.x;
  const int swz = (id & 7) * 64 + (id >> 3);   // bijective: 512 = 8*64
  const int m0 = (swz >> 4) * 128, n0 = (swz & 15) * 192;

  const int srow = tid >> 3;
  const int scol = ((tid & 7) ^ (srow & 7)) * 8;
  const __bf16* aSrc = A + (size_t)(m0 + srow) * K + scol;
  const __bf16* bSrc = Bt + (size_t)(n0 + srow) * K + scol;
  const int wb8 = (tid & 448) * 8;   // wave-uniform LDS base (elems)
  // buffers (elems): A0 @0 (8192), B0 @8192 (12288), A1 @20480, B1 @28672
  f32x4 acc[4][3] = {};

  stage5(aSrc, bSrc, smem, smem + 8192, wb8, 0);
  __syncthreads();

  for (int t = 0; t < 32; ++t) {
    __bf16* Ab = smem + (t & 1) * 20480;
    __bf16* Bb = Ab + 8192;
    if (t < 31) {
      __bf16* An = smem + ((t + 1) & 1) * 20480;
      stage5(aSrc, bSrc, An, An + 8192, wb8, (size_t)(t + 1) * 64);
    }
    bf16x8 bF[3][2];
#pragma unroll
    for (int j = 0; j < 3; ++j) {
      int RB = wn * 48 + j * 16 + c15;
#pragma unroll
      for (int h = 0; h < 2; ++h)
        bF[j][h] = *(const bf16x8*)(Bb + RB * 64 + (((h * 4 + quad) ^ (RB & 7)) * 8));
    }
    __builtin_amdgcn_s_setprio(1);
#pragma unroll
    for (int i = 0; i < 4; ++i) {
      int RA = wm * 64 + i * 16 + c15;
      bf16x8 a0 = *(const bf16x8*)(Ab + RA * 64 + ((quad ^ (RA & 7)) * 8));
      bf16x8 a1 = *(const bf16x8*)(Ab + RA * 64 + (((4 + quad) ^ (RA & 7)) * 8));
#pragma unroll
      for (int j = 0; j < 3; ++j) {
        acc[i][j] = __builtin_amdgcn_mfma_f32_16x16x32_bf16(a0, bF[j][0], acc[i][j], 0, 0, 0);
        acc[i][j] = __builtin_amdgcn_mfma_f32_16x16x32_bf16(a1, bF[j][1], acc[i][j], 0, 0, 0);
      }
    }
    __builtin_amdgcn_s_setprio(0);
    __syncthreads();
  }

  // ---- epilogue: per-wave 10KB LDS chunk; waves independent (no cross-wave sync).
  const int b = m0 >> 11;
  const int s0 = m0 & 2047;
  const int colbase = n0 + wn * 48;
  __bf16* st = smem + w * 5120;

#pragma unroll
  for (int i = 0; i < 4; ++i)
#pragma unroll
    for (int j = 0; j < 3; ++j)
#pragma unroll
      for (int r = 0; r < 4; ++r)
        st[(i * 16 + quad * 4 + r) * 56 + j * 16 + c15] = (__bf16)acc[i][j][r];
  __syncthreads();

  // Q/K granules: coalesced 16B row chunks
  {
    const int g = lane & 7, sl = lane >> 3;
    int c = colbase + g * 8;
    if (g < 6 && c < 2560) {
      __bf16* hp = (c < 2048)
          ? Qb + (((size_t)b * 16 + (c >> 7)) * 2048 + s0 + wm * 64) * 128 + (c & 127)
          : Kb + (((size_t)b * 4 + ((c - 2048) >> 7)) * 2048 + s0 + wm * 64) * 128 + (c & 127);
#pragma unroll
      for (int it = 0; it < 8; ++it) {
        int s = it * 8 + sl;
        *(bf16x8*)(hp + (size_t)s * 128) = *(const bf16x8*)(st + s * 56 + g * 8);
      }
    }
  }
  // V granules: transpose via column gather, 16B contiguous-in-s writes
#pragma unroll
  for (int it = 0; it < 6; ++it) {
    int lc = it * 8 + (lane >> 3);
    int c = colbase + lc;
    if (c >= 2560) {
      int sc = lane & 7;
      bf16x8 o;
#pragma unroll
      for (int rr = 0; rr < 8; ++rr) o[rr] = st[(sc * 8 + rr) * 56 + lc];
      __bf16* vp = Vt + (((size_t)b * 4 + ((c - 2560) >> 7)) * 128 + ((c - 2560) & 127)) * 2048
                   + s0 + wm * 64 + sc * 8;
      *(bf16x8*)vp = o;
    }
  }
}

// ---------------- RMSNorm + RoPE, in-place on bf16 Q/K ----------------
__global__ __launch_bounds__(256) void norm_rope(
    __bf16* __restrict__ Qb, __bf16* __restrict__ Kb,
    const float* __restrict__ qw, const float* __restrict__ kw,
    const float* __restrict__ cosT, const float* __restrict__ sinT) {
  const int tid = threadIdx.x, w = tid >> 6, lane = tid & 63;
  const int v = blockIdx.x * 4 + w;
  const bool isQ = v < 65536;
  __bf16* base = isQ ? Qb + (size_t)v * 128 : Kb + (size_t)(v - 65536) * 128;
  const int s = v & 2047;
  float x1 = (float)base[lane], x2 = (float)base[lane + 64];
  float ss = x1 * x1 + x2 * x2;
#pragma unroll
  for (int d = 32; d; d >>= 1) ss += __shfl_xor(ss, d);
  float rn = rsqrtf(ss * (1.0f / 128.0f) + 1e-8f);
  const float* wt = isQ ? qw : kw;
  float n1 = x1 * rn * (1.0f + wt[lane]);
  float n2 = x2 * rn * (1.0f + wt[lane + 64]);
  float c1 = cosT[s * 128 + lane], c2 = cosT[s * 128 + 64 + lane];
  float s1 = sinT[s * 128 + lane], s2 = sinT[s * 128 + 64 + lane];
  const float QSC = 0.08838834764831845f * 1.4426950408889634f;  // scale * log2(e)
  float post = isQ ? QSC : 1.0f;
  base[lane]      = (__bf16)((n1 * c1 - n2 * s1) * post);
  base[lane + 64] = (__bf16)((n2 * c2 + n1 * s2) * post);
}

// ---------------- output projection: 128x128 tile, BK=64, safe 2-phase dbuf -------
__device__ __forceinline__ void stage4(const __bf16* aS, const __bf16* bS,
                                       __bf16* Ab, __bf16* Bb, int wb8, size_t kt) {
#pragma unroll
  for (int l = 0; l < 2; ++l)
    gload_lds16(aS + (size_t)l * 131072 + kt, Ab + l * 4096 + wb8);
#pragma unroll
  for (int l = 0; l < 2; ++l)
    gload_lds16(bS + (size_t)l * 131072 + kt, Bb + l * 4096 + wb8);
}

__global__ __launch_bounds__(512, 4) void gemm_bt128(
    const __bf16* __restrict__ A, const __bf16* __restrict__ Bt,
    float* __restrict__ C) {
  extern __shared__ __bf16 smem[];
  const int K = 2048, N = 2048;
  const int tid = threadIdx.x;
  const int lane = tid & 63, w = tid >> 6;
  const int c15 = lane & 15, quad = lane >> 4;
  const int wm = w >> 2, wn = w & 3;
  const int id = blockIdx.x;
  const int swz = (id & 7) * 64 + (id >> 3);   // bijective: 512 = 8*64
  const int m0 = (swz >> 4) * 128, n0 = (swz & 15) * 128;

  const int srow = tid >> 3;
  const int scol = ((tid & 7) ^ (srow & 7)) * 8;
  const __bf16* aSrc = A + (size_t)(m0 + srow) * K + scol;
  const __bf16* bSrc = Bt + (size_t)(n0 + srow) * K + scol;
  const int wb8 = (tid & 448) * 8;

  f32x4 acc[4][2] = {};

  stage4(aSrc, bSrc, smem, smem + 8192, wb8, 0);
  __syncthreads();

  for (int t = 0; t < 32; ++t) {
    __bf16* Ab = smem + (t & 1) * 16384;
    __bf16* Bb = Ab + 8192;
    if (t < 31) {
      __bf16* An = smem + ((t + 1) & 1) * 16384;
      stage4(aSrc, bSrc, An, An + 8192, wb8, (size_t)(t + 1) * 64);
    }
    bf16x8 bF[2][2];
#pragma unroll
    for (int j = 0; j < 2; ++j) {
      int RB = wn * 32 + j * 16 + c15;
#pragma unroll
      for (int h = 0; h < 2; ++h)
        bF[j][h] = *(const bf16x8*)(Bb + RB * 64 + (((h * 4 + quad) ^ (RB & 7)) * 8));
    }
    __builtin_amdgcn_s_setprio(1);
#pragma unroll
    for (int i = 0; i < 4; ++i) {
      int RA = wm * 64 + i * 16 + c15;
      bf16x8 a0 = *(const bf16x8*)(Ab + RA * 64 + ((quad ^ (RA & 7)) * 8));
      bf16x8 a1 = *(const bf16x8*)(Ab + RA * 64 + (((4 + quad) ^ (RA & 7)) * 8));
#pragma unroll
      for (int j = 0; j < 2; ++j) {
        acc[i][j] = __builtin_amdgcn_mfma_f32_16x16x32_bf16(a0, bF[j][0], acc[i][j], 0, 0, 0);
        acc[i][j] = __builtin_amdgcn_mfma_f32_16x16x32_bf16(a1, bF[j][1], acc[i][j], 0, 0, 0);
      }
    }
    __builtin_amdgcn_s_setprio(0);
    __syncthreads();
  }

#pragma unroll
  for (int i = 0; i < 4; ++i) {
    int r0 = m0 + wm * 64 + i * 16 + quad * 4;
#pragma unroll
    for (int j = 0; j < 2; ++j) {
      int cc = n0 + wn * 32 + j * 16 + c15;
#pragma unroll
      for (int r = 0; r < 4; ++r)
        C[(size_t)(r0 + r) * N + cc] = acc[i][j][r];
    }
  }
}

// ---------------- Flash attention v5: 32 q-rows/wave, K-dbuf async staging --------
// Schedule per KV tile (2 syncs, drain hidden under QK^T+softmax):
//   A: __syncthreads  [prev PV's Vs reads done; prev-iter K stage drained]
//   B: stage Vs <- V(t); stage Ks[(t+1)&1] <- K(t+1)   (async, stays in flight)
//   C: QK^T from Ks[t&1] + softmax + P-store           (hides B's L2 latency)
//   D: __syncthreads  [implicit vmcnt(0): B landed; Vs/Ks[t+1] valid]
//   E: PV from Vs
// Safety: Ks[t&1] staged at (t-1).B, drained by A(t); Vs overwritten at B only
// after A(t) confirms PV(t-1) reads done; D covers B before E reads.
// LDS 66 KiB dynamic (Ks x2 32K + Vs 16K + Ps 18K) -> 2 blocks/CU.
__global__ __launch_bounds__(256) void attn(
    const __bf16* __restrict__ Qb, const __bf16* __restrict__ Kb,
    const __bf16* __restrict__ Vt, const unsigned char* __restrict__ pad,
    const unsigned char* __restrict__ pad64, const int* __restrict__ winp,
    __bf16* __restrict__ O) {
  const int S = 2048;
  extern __shared__ __bf16 smem[];
  __bf16* Vs = smem + 16384;            // [128 d][64 s]
  __bf16* Ps = smem + 24576;            // [4 waves][32 q][72]
  const int tid = threadIdx.x, w = tid >> 6, lane = tid & 63;
  const int c15 = lane & 15, quad = lane >> 4;
  const int b = blockIdx.z;
  const int bx = (b == 0) ? blockIdx.x : (gridDim.x - 1 - blockIdx.x);
  const int q0 = ((int)gridDim.x - 1 - bx) * 32;
  const int kv = blockIdx.y;
  const int h = kv * 4 + w;
  const int W = *winp;
  const unsigned char* padb = pad + (size_t)b * S;
  const unsigned char* pad64b = pad64 + b * 32;
  const __bf16* Qh = Qb + (((size_t)b * 16 + h) * S) * 128;
  const __bf16* Kh = Kb + (((size_t)b * 4 + kv) * S) * 128;
  const __bf16* Vh = Vt + (((size_t)b * 4 + kv) * 128) * (size_t)S;
  __bf16* Pw = Ps + w * 32 * 72;

  bf16x8 qf0[4], qf1[4];
#pragma unroll
  for (int c = 0; c < 4; ++c) {
    qf0[c] = *(const bf16x8*)(Qh + (size_t)(q0 + c15) * 128 + c * 32 + quad * 8);
    qf1[c] = *(const bf16x8*)(Qh + (size_t)(q0 + 16 + c15) * 128 + c * 32 + quad * 8);
  }

  f32x4 acc0[8] = {}, acc1[8] = {};
  float lsum0[4] = {0.f, 0.f, 0.f, 0.f};
  float lsum1[4] = {0.f, 0.f, 0.f, 0.f};

  const int krow_i = lane >> 4, kch = lane & 15;
  const int vrow_i = lane >> 3, vch = lane & 7;

  int kb0 = q0 - W; if (kb0 < 0) kb0 = 0; kb0 &= ~63;
  const int kbend = q0 + 31;

  // prologue: stage K(kb0) into Ks buffer 0
#pragma unroll
  for (int i = 0; i < 4; ++i) {
    int row = w * 16 + i * 4 + krow_i;
    gload_lds16(Kh + (size_t)(kb0 + row) * 128 + ((kch ^ (row & 15)) * 8),
                smem + (w * 16 + i * 4) * 128);
  }

  int ti = 0;
  for (int kb = kb0; kb <= kbend; kb += 64, ++ti) {
    __bf16* Ksb = smem + (ti & 1) * 8192;
    __syncthreads();  // A
    // B: stage V(t) and K(t+1)
#pragma unroll
    for (int i = 0; i < 4; ++i) {
      int row = w * 32 + i * 8 + vrow_i;
      gload_lds16(Vh + (size_t)row * S + kb + ((vch ^ (row & 7)) * 8),
                  Vs + (w * 32 + i * 8) * 64);
    }
    if (kb + 64 <= kbend) {
      __bf16* Ksn = smem + ((ti + 1) & 1) * 8192;
#pragma unroll
      for (int i = 0; i < 4; ++i) {
        int row = w * 16 + i * 4 + krow_i;
        gload_lds16(Kh + (size_t)(kb + 64 + row) * 128 + ((kch ^ (row & 15)) * 8),
                    Ksn + (w * 16 + i * 4) * 128);
      }
    }

    // C: QK^T + softmax (hides B's latency)
    f32x4 sf0[4], sf1[4];
#pragma unroll
    for (int nb = 0; nb < 4; ++nb) {
      f32x4 ca = {}, cb = {};
#pragma unroll
      for (int c = 0; c < 4; ++c) {
        bf16x8 kf = *(const bf16x8*)(Ksb + (nb * 16 + c15) * 128 + (((c * 4 + quad) ^ c15) * 8));
        ca = __builtin_amdgcn_mfma_f32_16x16x32_bf16(qf0[c], kf, ca, 0, 0, 0);
        cb = __builtin_amdgcn_mfma_f32_16x16x32_bf16(qf1[c], kf, cb, 0, 0, 0);
      }
      sf0[nb] = ca; sf1[nb] = cb;
    }

    const bool fast = (kb + 63 <= q0) && (q0 + 31 - kb <= W) && (pad64b[kb >> 6] == 0);
    if (fast) {
#pragma unroll
      for (int r = 0; r < 4; ++r) {
        float a0 = exp2f(sf0[0][r]), a1 = exp2f(sf0[1][r]);
        float a2 = exp2f(sf0[2][r]), a3 = exp2f(sf0[3][r]);
        lsum0[r] += (a0 + a1) + (a2 + a3);
        int pr = (quad * 4 + r) * 72 + c15;
        Pw[pr] = (__bf16)a0; Pw[pr + 16] = (__bf16)a1;
        Pw[pr + 32] = (__bf16)a2; Pw[pr + 48] = (__bf16)a3;
        float b0 = exp2f(sf1[0][r]), b1 = exp2f(sf1[1][r]);
        float b2 = exp2f(sf1[2][r]), b3 = exp2f(sf1[3][r]);
        lsum1[r] += (b0 + b1) + (b2 + b3);
        int qr = pr + 16 * 72;
        Pw[qr] = (__bf16)b0; Pw[qr + 16] = (__bf16)b1;
        Pw[qr + 32] = (__bf16)b2; Pw[qr + 48] = (__bf16)b3;
      }
    } else {
#pragma unroll
      for (int r = 0; r < 4; ++r) {
        const int qi0 = q0 + quad * 4 + r;
        const int qi1 = qi0 + 16;
        float p0[4], p1[4];
#pragma unroll
        for (int nb = 0; nb < 4; ++nb) {
          int ki = kb + nb * 16 + c15;
          bool okp = (padb[ki] == 0);
          bool ok0 = (ki <= qi0) && ((qi0 - ki) <= W) && okp;
          bool ok1 = (ki <= qi1) && ((qi1 - ki) <= W) && okp;
          float e0 = exp2f(sf0[nb][r]);
          float e1 = exp2f(sf1[nb][r]);
          p0[nb] = ok0 ? e0 : 0.0f;
          p1[nb] = ok1 ? e1 : 0.0f;
        }
        lsum0[r] += (p0[0] + p0[1]) + (p0[2] + p0[3]);
        lsum1[r] += (p1[0] + p1[1]) + (p1[2] + p1[3]);
        int pr = (quad * 4 + r) * 72 + c15;
        Pw[pr] = (__bf16)p0[0]; Pw[pr + 16] = (__bf16)p0[1];
        Pw[pr + 32] = (__bf16)p0[2]; Pw[pr + 48] = (__bf16)p0[3];
        int qr = pr + 16 * 72;
        Pw[qr] = (__bf16)p1[0]; Pw[qr + 16] = (__bf16)p1[1];
        Pw[qr + 32] = (__bf16)p1[2]; Pw[qr + 48] = (__bf16)p1[3];
      }
    }

    __syncthreads();  // D: B's stages landed; Vs / Ks[t+1] valid

    // E: PV
    bf16x8 pf00 = *(const bf16x8*)(Pw + c15 * 72 + quad * 8);
    bf16x8 pf01 = *(const bf16x8*)(Pw + c15 * 72 + 32 + quad * 8);
    bf16x8 pf10 = *(const bf16x8*)(Pw + (16 + c15) * 72 + quad * 8);
    bf16x8 pf11 = *(const bf16x8*)(Pw + (16 + c15) * 72 + 32 + quad * 8);
#pragma unroll
    for (int nb = 0; nb < 8; ++nb) {
      int row = nb * 16 + c15;
      bf16x8 vf0 = *(const bf16x8*)(Vs + row * 64 + ((quad ^ (c15 & 7)) * 8));
      bf16x8 vf1 = *(const bf16x8*)(Vs + row * 64 + (((4 + quad) ^ (c15 & 7)) * 8));
      acc0[nb] = __builtin_amdgcn_mfma_f32_16x16x32_bf16(pf00, vf0, acc0[nb], 0, 0, 0);
      acc0[nb] = __builtin_amdgcn_mfma_f32_16x16x32_bf16(pf01, vf1, acc0[nb], 0, 0, 0);
      acc1[nb] = __builtin_amdgcn_mfma_f32_16x16x32_bf16(pf10, vf0, acc1[nb], 0, 0, 0);
      acc1[nb] = __builtin_amdgcn_mfma_f32_16x16x32_bf16(pf11, vf1, acc1[nb], 0, 0, 0);
    }
  }

#pragma unroll
  for (int r = 0; r < 4; ++r) {
    lsum0[r] += __shfl_xor(lsum0[r], 1);
    lsum0[r] += __shfl_xor(lsum0[r], 2);
    lsum0[r] += __shfl_xor(lsum0[r], 4);
    lsum0[r] += __shfl_xor(lsum0[r], 8);
    lsum1[r] += __shfl_xor(lsum1[r], 1);
    lsum1[r] += __shfl_xor(lsum1[r], 2);
    lsum1[r] += __shfl_xor(lsum1[r], 4);
    lsum1[r] += __shfl_xor(lsum1[r], 8);
  }
  float inv0[4], inv1[4];
#pragma unroll
  for (int r = 0; r < 4; ++r) { inv0[r] = 1.0f / lsum0[r]; inv1[r] = 1.0f / lsum1[r]; }
#pragma unroll
  for (int nb = 0; nb < 8; ++nb)
#pragma unroll
    for (int r = 0; r < 4; ++r) {
      size_t idx = ((size_t)b * S + q0 + quad * 4 + r) * 2048 + h * 128 + nb * 16 + c15;
      O[idx] = (__bf16)(acc0[nb][r] * inv0[r]);
      O[idx + (size_t)16 * 2048] = (__bf16)(acc1[nb][r] * inv1[r]);
    }
}

// ---------------- launch ----------------
extern "C" void kernel_launch(void* const* d_in, const int* in_sizes, int n_in,
                              void* d_out, int out_size, void* d_ws, size_t ws_size,
                              hipStream_t stream) {
  const float* x    = (const float*)d_in[0];
  const float* Wq   = (const float*)d_in[1];
  const float* Wk   = (const float*)d_in[2];
  const float* Wv   = (const float*)d_in[3];
  const float* Wo   = (const float*)d_in[4];
  const float* qw   = (const float*)d_in[5];
  const float* kw   = (const float*)d_in[6];
  const float* cosT = (const float*)d_in[7];
  const float* sinT = (const float*)d_in[8];
  const unsigned char* pad = (const unsigned char*)d_in[9];
  const int* win    = (const int*)d_in[10];

  char* ws = (char*)d_ws;
  __bf16* xb    = (__bf16*)(ws + 0);          // 4096x2048 bf16        (16 MB)
  __bf16* Wqkvt = (__bf16*)(ws + 16777216);   // 3072x2048 bf16        (12 MB)
  __bf16* Wot   = (__bf16*)(ws + 29360128);   // 2048x2048 bf16        (8 MB)
  __bf16* Qb    = (__bf16*)(ws + 37748736);   // [2][16][2048][128]    (16 MB)
  __bf16* Kb    = (__bf16*)(ws + 54525952);   // [2][4][2048][128]     (4 MB)
  __bf16* Vt    = (__bf16*)(ws + 58720256);   // [2][4][128][2048]     (4 MB)
  __bf16* Ob    = (__bf16*)(ws + 62914560);   // 4096x2048 bf16        (16 MB)
  unsigned char* pad64 = (unsigned char*)(ws + 79691776);  // [2][32]

  static int qkv_attr = (int)hipFuncSetAttribute(
      (const void*)gemm_qkv192, hipFuncAttributeMaxDynamicSharedMemorySize, 81920);
  (void)qkv_attr;
  static int bt_attr = (int)hipFuncSetAttribute(
      (const void*)gemm_bt128, hipFuncAttributeMaxDynamicSharedMemorySize, 65536);
  (void)bt_attr;
  static int at_attr = (int)hipFuncSetAttribute(
      (const void*)attn, hipFuncAttributeMaxDynamicSharedMemorySize, 67584);
  (void)at_attr;

  prep<<<dim3(288, 64, 1), dim3(32, 8, 1), 0, stream>>>(
      Wq, Wk, Wv, Wo, (const float4*)x, (const unsigned long long*)pad,
      Wqkvt, Wot, (bf16x4*)xb, pad64);

  gemm_qkv192<<<dim3(512, 1, 1), 512, 81920, stream>>>(xb, Wqkvt, Qb, Kb, Vt);

  norm_rope<<<20480, 256, 0, stream>>>(Qb, Kb, qw, kw, cosT, sinT);

  attn<<<dim3(64, 4, 2), 256, 67584, stream>>>(Qb, Kb, Vt, pad, pad64, win, Ob);

  gemm_bt128<<<dim3(512, 1, 1), 512, 65536, stream>>>(Ob, Wot, (float*)d_out);
}

// Round 7
// 295.514 us; speedup vs baseline: 1.0915x; 1.0105x over previous
//
#include <hip/hip_runtime.h>

typedef __attribute__((ext_vector_type(4))) float f32x4;
typedef __attribute__((ext_vector_type(8))) __bf16 bf16x8;
typedef __attribute__((ext_vector_type(4))) __bf16 bf16x4;

__device__ __forceinline__ void gload_lds16(const __bf16* g, __bf16* l) {
  __builtin_amdgcn_global_load_lds(
      (const __attribute__((address_space(1))) unsigned int*)(g),
      (__attribute__((address_space(3))) unsigned int*)(l), 16, 0, 0);
}

// ---------------- prep: weight transposes + x convert + pad_or, one launch --------
__global__ __launch_bounds__(256) void prep(
    const float* __restrict__ Wq, const float* __restrict__ Wk,
    const float* __restrict__ Wv, const float* __restrict__ Wo,
    const float4* __restrict__ x, const unsigned long long* __restrict__ pad,
    __bf16* __restrict__ Wqkvt, __bf16* __restrict__ Wot,
    bf16x4* __restrict__ xb, unsigned char* __restrict__ pad64) {
  const int bx = blockIdx.x, by = blockIdx.y;
  const int tx = threadIdx.x, ty = threadIdx.y;
  const int tid = ty * 32 + tx;
  if (bx >= 160) {
    int i = ((bx - 160) * 64 + by) * 256 + tid;
    float4 v = x[i];
    bf16x4 o = {(__bf16)v.x, (__bf16)v.y, (__bf16)v.z, (__bf16)v.w};
    xb[i] = o;
    return;
  }
  if (bx == 0 && by == 0 && tid < 64) {
    unsigned long long acc = 0;
#pragma unroll
    for (int i = 0; i < 8; ++i) acc |= pad[tid * 8 + i];
    pad64[tid] = (acc != 0) ? 1 : 0;
  }
  __shared__ float t[32][33];
  const float* src; __bf16* dst; int ss, c0;
  if (bx < 64)      { src = Wq; dst = Wqkvt;                       ss = 2048; c0 = bx * 32; }
  else if (bx < 80) { src = Wk; dst = Wqkvt + (size_t)2048 * 2048; ss = 512;  c0 = (bx - 64) * 32; }
  else if (bx < 96) { src = Wv; dst = Wqkvt + (size_t)2560 * 2048; ss = 512;  c0 = (bx - 80) * 32; }
  else              { src = Wo; dst = Wot;                         ss = 2048; c0 = (bx - 96) * 32; }
  const int r0 = by * 32;
#pragma unroll
  for (int i = ty; i < 32; i += 8)
    t[i][tx] = src[(size_t)(r0 + i) * ss + c0 + tx];
  __syncthreads();
#pragma unroll
  for (int i = ty; i < 32; i += 8)
    dst[(size_t)(c0 + i) * 2048 + r0 + tx] = (__bf16)t[tx][i];
}

// ---------------- QKV GEMM: 128x192 tile, BK=64, safe 2-phase double-buffer -------
__device__ __forceinline__ void stage5(const __bf16* aS, const __bf16* bS,
                                       __bf16* Ab, __bf16* Bb, int wb8, size_t kt) {
#pragma unroll
  for (int l = 0; l < 2; ++l)
    gload_lds16(aS + (size_t)l * 131072 + kt, Ab + l * 4096 + wb8);
#pragma unroll
  for (int l = 0; l < 3; ++l)
    gload_lds16(bS + (size_t)l * 131072 + kt, Bb + l * 4096 + wb8);
}

__global__ __launch_bounds__(512, 4) void gemm_qkv192(
    const __bf16* __restrict__ A, const __bf16* __restrict__ Bt,
    __bf16* __restrict__ Qb, __bf16* __restrict__ Kb, __bf16* __restrict__ Vt) {
  extern __shared__ __bf16 smem[];
  const int K = 2048;
  const int tid = threadIdx.x;
  const int lane = tid & 63, w = tid >> 6;
  const int c15 = lane & 15, quad = lane >> 4;
  const int wm = w >> 2, wn = w & 3;
  const int id = blockIdx.x;
  const int swz = (id & 7) * 64 + (id >> 3);   // bijective: 512 = 8*64
  const int m0 = (swz >> 4) * 128, n0 = (swz & 15) * 192;

  const int srow = tid >> 3;
  const int scol = ((tid & 7) ^ (srow & 7)) * 8;
  const __bf16* aSrc = A + (size_t)(m0 + srow) * K + scol;
  const __bf16* bSrc = Bt + (size_t)(n0 + srow) * K + scol;
  const int wb8 = (tid & 448) * 8;   // wave-uniform LDS base (elems)
  // buffers (elems): A0 @0 (8192), B0 @8192 (12288), A1 @20480, B1 @28672
  f32x4 acc[4][3] = {};

  stage5(aSrc, bSrc, smem, smem + 8192, wb8, 0);
  __syncthreads();

  for (int t = 0; t < 32; ++t) {
    __bf16* Ab = smem + (t & 1) * 20480;
    __bf16* Bb = Ab + 8192;
    if (t < 31) {
      __bf16* An = smem + ((t + 1) & 1) * 20480;
      stage5(aSrc, bSrc, An, An + 8192, wb8, (size_t)(t + 1) * 64);
    }
    bf16x8 bF[3][2];
#pragma unroll
    for (int j = 0; j < 3; ++j) {
      int RB = wn * 48 + j * 16 + c15;
#pragma unroll
      for (int h = 0; h < 2; ++h)
        bF[j][h] = *(const bf16x8*)(Bb + RB * 64 + (((h * 4 + quad) ^ (RB & 7)) * 8));
    }
    __builtin_amdgcn_s_setprio(1);
#pragma unroll
    for (int i = 0; i < 4; ++i) {
      int RA = wm * 64 + i * 16 + c15;
      bf16x8 a0 = *(const bf16x8*)(Ab + RA * 64 + ((quad ^ (RA & 7)) * 8));
      bf16x8 a1 = *(const bf16x8*)(Ab + RA * 64 + (((4 + quad) ^ (RA & 7)) * 8));
#pragma unroll
      for (int j = 0; j < 3; ++j) {
        acc[i][j] = __builtin_amdgcn_mfma_f32_16x16x32_bf16(a0, bF[j][0], acc[i][j], 0, 0, 0);
        acc[i][j] = __builtin_amdgcn_mfma_f32_16x16x32_bf16(a1, bF[j][1], acc[i][j], 0, 0, 0);
      }
    }
    __builtin_amdgcn_s_setprio(0);
    __syncthreads();
  }

  // ---- epilogue: per-wave 10KB LDS chunk; waves independent (no cross-wave sync).
  const int b = m0 >> 11;
  const int s0 = m0 & 2047;
  const int colbase = n0 + wn * 48;
  __bf16* st = smem + w * 5120;

#pragma unroll
  for (int i = 0; i < 4; ++i)
#pragma unroll
    for (int j = 0; j < 3; ++j)
#pragma unroll
      for (int r = 0; r < 4; ++r)
        st[(i * 16 + quad * 4 + r) * 56 + j * 16 + c15] = (__bf16)acc[i][j][r];
  __syncthreads();

  // Q/K granules: coalesced 16B row chunks
  {
    const int g = lane & 7, sl = lane >> 3;
    int c = colbase + g * 8;
    if (g < 6 && c < 2560) {
      __bf16* hp = (c < 2048)
          ? Qb + (((size_t)b * 16 + (c >> 7)) * 2048 + s0 + wm * 64) * 128 + (c & 127)
          : Kb + (((size_t)b * 4 + ((c - 2048) >> 7)) * 2048 + s0 + wm * 64) * 128 + (c & 127);
#pragma unroll
      for (int it = 0; it < 8; ++it) {
        int s = it * 8 + sl;
        *(bf16x8*)(hp + (size_t)s * 128) = *(const bf16x8*)(st + s * 56 + g * 8);
      }
    }
  }
  // V granules: transpose via column gather, 16B contiguous-in-s writes
#pragma unroll
  for (int it = 0; it < 6; ++it) {
    int lc = it * 8 + (lane >> 3);
    int c = colbase + lc;
    if (c >= 2560) {
      int sc = lane & 7;
      bf16x8 o;
#pragma unroll
      for (int rr = 0; rr < 8; ++rr) o[rr] = st[(sc * 8 + rr) * 56 + lc];
      __bf16* vp = Vt + (((size_t)b * 4 + ((c - 2560) >> 7)) * 128 + ((c - 2560) & 127)) * 2048
                   + s0 + wm * 64 + sc * 8;
      *(bf16x8*)vp = o;
    }
  }
}

// ---------------- RMSNorm + RoPE, in-place on bf16 Q/K ----------------
__global__ __launch_bounds__(256) void norm_rope(
    __bf16* __restrict__ Qb, __bf16* __restrict__ Kb,
    const float* __restrict__ qw, const float* __restrict__ kw,
    const float* __restrict__ cosT, const float* __restrict__ sinT) {
  const int tid = threadIdx.x, w = tid >> 6, lane = tid & 63;
  const int v = blockIdx.x * 4 + w;
  const bool isQ = v < 65536;
  __bf16* base = isQ ? Qb + (size_t)v * 128 : Kb + (size_t)(v - 65536) * 128;
  const int s = v & 2047;
  float x1 = (float)base[lane], x2 = (float)base[lane + 64];
  float ss = x1 * x1 + x2 * x2;
#pragma unroll
  for (int d = 32; d; d >>= 1) ss += __shfl_xor(ss, d);
  float rn = rsqrtf(ss * (1.0f / 128.0f) + 1e-8f);
  const float* wt = isQ ? qw : kw;
  float n1 = x1 * rn * (1.0f + wt[lane]);
  float n2 = x2 * rn * (1.0f + wt[lane + 64]);
  float c1 = cosT[s * 128 + lane], c2 = cosT[s * 128 + 64 + lane];
  float s1 = sinT[s * 128 + lane], s2 = sinT[s * 128 + 64 + lane];
  const float QSC = 0.08838834764831845f * 1.4426950408889634f;  // scale * log2(e)
  float post = isQ ? QSC : 1.0f;
  base[lane]      = (__bf16)((n1 * c1 - n2 * s1) * post);
  base[lane + 64] = (__bf16)((n2 * c2 + n1 * s2) * post);
}

// ---------------- output projection: 128x128 tile, BK=64, safe 2-phase dbuf -------
__device__ __forceinline__ void stage4(const __bf16* aS, const __bf16* bS,
                                       __bf16* Ab, __bf16* Bb, int wb8, size_t kt) {
#pragma unroll
  for (int l = 0; l < 2; ++l)
    gload_lds16(aS + (size_t)l * 131072 + kt, Ab + l * 4096 + wb8);
#pragma unroll
  for (int l = 0; l < 2; ++l)
    gload_lds16(bS + (size_t)l * 131072 + kt, Bb + l * 4096 + wb8);
}

__global__ __launch_bounds__(512, 4) void gemm_bt128(
    const __bf16* __restrict__ A, const __bf16* __restrict__ Bt,
    float* __restrict__ C) {
  extern __shared__ __bf16 smem[];
  const int K = 2048, N = 2048;
  const int tid = threadIdx.x;
  const int lane = tid & 63, w = tid >> 6;
  const int c15 = lane & 15, quad = lane >> 4;
  const int wm = w >> 2, wn = w & 3;
  const int id = blockIdx.x;
  const int swz = (id & 7) * 64 + (id >> 3);   // bijective: 512 = 8*64
  const int m0 = (swz >> 4) * 128, n0 = (swz & 15) * 128;

  const int srow = tid >> 3;
  const int scol = ((tid & 7) ^ (srow & 7)) * 8;
  const __bf16* aSrc = A + (size_t)(m0 + srow) * K + scol;
  const __bf16* bSrc = Bt + (size_t)(n0 + srow) * K + scol;
  const int wb8 = (tid & 448) * 8;

  f32x4 acc[4][2] = {};

  stage4(aSrc, bSrc, smem, smem + 8192, wb8, 0);
  __syncthreads();

  for (int t = 0; t < 32; ++t) {
    __bf16* Ab = smem + (t & 1) * 16384;
    __bf16* Bb = Ab + 8192;
    if (t < 31) {
      __bf16* An = smem + ((t + 1) & 1) * 16384;
      stage4(aSrc, bSrc, An, An + 8192, wb8, (size_t)(t + 1) * 64);
    }
    bf16x8 bF[2][2];
#pragma unroll
    for (int j = 0; j < 2; ++j) {
      int RB = wn * 32 + j * 16 + c15;
#pragma unroll
      for (int h = 0; h < 2; ++h)
        bF[j][h] = *(const bf16x8*)(Bb + RB * 64 + (((h * 4 + quad) ^ (RB & 7)) * 8));
    }
    __builtin_amdgcn_s_setprio(1);
#pragma unroll
    for (int i = 0; i < 4; ++i) {
      int RA = wm * 64 + i * 16 + c15;
      bf16x8 a0 = *(const bf16x8*)(Ab + RA * 64 + ((quad ^ (RA & 7)) * 8));
      bf16x8 a1 = *(const bf16x8*)(Ab + RA * 64 + (((4 + quad) ^ (RA & 7)) * 8));
#pragma unroll
      for (int j = 0; j < 2; ++j) {
        acc[i][j] = __builtin_amdgcn_mfma_f32_16x16x32_bf16(a0, bF[j][0], acc[i][j], 0, 0, 0);
        acc[i][j] = __builtin_amdgcn_mfma_f32_16x16x32_bf16(a1, bF[j][1], acc[i][j], 0, 0, 0);
      }
    }
    __builtin_amdgcn_s_setprio(0);
    __syncthreads();
  }

#pragma unroll
  for (int i = 0; i < 4; ++i) {
    int r0 = m0 + wm * 64 + i * 16 + quad * 4;
#pragma unroll
    for (int j = 0; j < 2; ++j) {
      int cc = n0 + wn * 32 + j * 16 + c15;
#pragma unroll
      for (int r = 0; r < 4; ++r)
        C[(size_t)(r0 + r) * N + cc] = acc[i][j][r];
    }
  }
}

// ---------------- Flash attention v6: swapped QK^T, packed b64 P-stores ----------
// Swapped QK: ca = mfma(kf, qf) -- A/B fragment lane layouts are identical for
// 16x16x32, so the same register fragments work; output becomes
// sf[nb][r] = S[k = kb+nb*16+quad*4+r][q = q0+c15]: each lane holds 4 CONSECUTIVE
// k for one q. P-store = cvt_pk x2 + one ds_write_b64 per nb per sub (8 b64/iter
// vs 32 ds_write_u16). lsum is scalar per sub (q=c15); reduce = 2 shfl_xor at end;
// inv redistributed to writer lanes by 8 end-only shfls. PV path unchanged
// (LDS P layout [q][k] stride 72 identical).
// Dispatch: heavy q-tiles first in BOTH batches (R0's b=1 reversal made the
// heaviest blocks dispatch last -> serial tail; removed).
__global__ __launch_bounds__(256) void attn(
    const __bf16* __restrict__ Qb, const __bf16* __restrict__ Kb,
    const __bf16* __restrict__ Vt, const unsigned char* __restrict__ pad,
    const unsigned char* __restrict__ pad64, const int* __restrict__ winp,
    __bf16* __restrict__ O) {
  const int S = 2048;
  extern __shared__ __bf16 smem[];
  __bf16* Vs = smem + 16384;            // [128 d][64 s]
  __bf16* Ps = smem + 24576;            // [4 waves][32 q][72]
  const int tid = threadIdx.x, w = tid >> 6, lane = tid & 63;
  const int c15 = lane & 15, quad = lane >> 4;
  const int b = blockIdx.z;
  const int q0 = ((int)gridDim.x - 1 - (int)blockIdx.x) * 32;
  const int kv = blockIdx.y;
  const int h = kv * 4 + w;
  const int W = *winp;
  const unsigned char* padb = pad + (size_t)b * S;
  const unsigned char* pad64b = pad64 + b * 32;
  const __bf16* Qh = Qb + (((size_t)b * 16 + h) * S) * 128;
  const __bf16* Kh = Kb + (((size_t)b * 4 + kv) * S) * 128;
  const __bf16* Vh = Vt + (((size_t)b * 4 + kv) * 128) * (size_t)S;
  __bf16* Pw = Ps + w * 32 * 72;

  bf16x8 qf0[4], qf1[4];
#pragma unroll
  for (int c = 0; c < 4; ++c) {
    qf0[c] = *(const bf16x8*)(Qh + (size_t)(q0 + c15) * 128 + c * 32 + quad * 8);
    qf1[c] = *(const bf16x8*)(Qh + (size_t)(q0 + 16 + c15) * 128 + c * 32 + quad * 8);
  }

  f32x4 acc0[8] = {}, acc1[8] = {};
  float lsum0 = 0.f, lsum1 = 0.f;
  const int qi0 = q0 + c15, qi1 = q0 + 16 + c15;

  const int krow_i = lane >> 4, kch = lane & 15;
  const int vrow_i = lane >> 3, vch = lane & 7;

  int kb0 = q0 - W; if (kb0 < 0) kb0 = 0; kb0 &= ~63;
  const int kbend = q0 + 31;

  // prologue: stage K(kb0) into Ks buffer 0
#pragma unroll
  for (int i = 0; i < 4; ++i) {
    int row = w * 16 + i * 4 + krow_i;
    gload_lds16(Kh + (size_t)(kb0 + row) * 128 + ((kch ^ (row & 15)) * 8),
                smem + (w * 16 + i * 4) * 128);
  }

  int ti = 0;
  for (int kb = kb0; kb <= kbend; kb += 64, ++ti) {
    __bf16* Ksb = smem + (ti & 1) * 8192;
    __syncthreads();  // A
    // B: stage V(t) and K(t+1)
#pragma unroll
    for (int i = 0; i < 4; ++i) {
      int row = w * 32 + i * 8 + vrow_i;
      gload_lds16(Vh + (size_t)row * S + kb + ((vch ^ (row & 7)) * 8),
                  Vs + (w * 32 + i * 8) * 64);
    }
    if (kb + 64 <= kbend) {
      __bf16* Ksn = smem + ((ti + 1) & 1) * 8192;
#pragma unroll
      for (int i = 0; i < 4; ++i) {
        int row = w * 16 + i * 4 + krow_i;
        gload_lds16(Kh + (size_t)(kb + 64 + row) * 128 + ((kch ^ (row & 15)) * 8),
                    Ksn + (w * 16 + i * 4) * 128);
      }
    }

    // C: swapped QK^T + softmax (hides B's latency)
    f32x4 sf0[4], sf1[4];
#pragma unroll
    for (int nb = 0; nb < 4; ++nb) {
      f32x4 ca = {}, cb = {};
#pragma unroll
      for (int c = 0; c < 4; ++c) {
        bf16x8 kf = *(const bf16x8*)(Ksb + (nb * 16 + c15) * 128 + (((c * 4 + quad) ^ c15) * 8));
        ca = __builtin_amdgcn_mfma_f32_16x16x32_bf16(kf, qf0[c], ca, 0, 0, 0);
        cb = __builtin_amdgcn_mfma_f32_16x16x32_bf16(kf, qf1[c], cb, 0, 0, 0);
      }
      sf0[nb] = ca; sf1[nb] = cb;
    }

    const bool fast = (kb + 63 <= q0) && (q0 + 31 - kb <= W) && (pad64b[kb >> 6] == 0);
    if (fast) {
#pragma unroll
      for (int nb = 0; nb < 4; ++nb) {
        float a0 = exp2f(sf0[nb][0]), a1 = exp2f(sf0[nb][1]);
        float a2 = exp2f(sf0[nb][2]), a3 = exp2f(sf0[nb][3]);
        lsum0 += (a0 + a1) + (a2 + a3);
        unsigned int w0, w1;
        asm("v_cvt_pk_bf16_f32 %0, %1, %2" : "=v"(w0) : "v"(a0), "v"(a1));
        asm("v_cvt_pk_bf16_f32 %0, %1, %2" : "=v"(w1) : "v"(a2), "v"(a3));
        unsigned long long pk0 = (unsigned long long)w0 | ((unsigned long long)w1 << 32);
        *(unsigned long long*)(Pw + (size_t)c15 * 72 + nb * 16 + quad * 4) = pk0;
        float b0 = exp2f(sf1[nb][0]), b1 = exp2f(sf1[nb][1]);
        float b2 = exp2f(sf1[nb][2]), b3 = exp2f(sf1[nb][3]);
        lsum1 += (b0 + b1) + (b2 + b3);
        unsigned int w2, w3;
        asm("v_cvt_pk_bf16_f32 %0, %1, %2" : "=v"(w2) : "v"(b0), "v"(b1));
        asm("v_cvt_pk_bf16_f32 %0, %1, %2" : "=v"(w3) : "v"(b2), "v"(b3));
        unsigned long long pk1 = (unsigned long long)w2 | ((unsigned long long)w3 << 32);
        *(unsigned long long*)(Pw + (size_t)(16 + c15) * 72 + nb * 16 + quad * 4) = pk1;
      }
    } else {
#pragma unroll
      for (int nb = 0; nb < 4; ++nb) {
        float p0[4], p1[4];
#pragma unroll
        for (int r = 0; r < 4; ++r) {
          int ki = kb + nb * 16 + quad * 4 + r;
          bool okp = (padb[ki] == 0);
          bool ok0 = (ki <= qi0) && ((qi0 - ki) <= W) && okp;
          bool ok1 = (ki <= qi1) && ((qi1 - ki) <= W) && okp;
          float e0 = exp2f(sf0[nb][r]);
          float e1 = exp2f(sf1[nb][r]);
          p0[r] = ok0 ? e0 : 0.0f;
          p1[r] = ok1 ? e1 : 0.0f;
        }
        lsum0 += (p0[0] + p0[1]) + (p0[2] + p0[3]);
        lsum1 += (p1[0] + p1[1]) + (p1[2] + p1[3]);
        unsigned int w0, w1, w2, w3;
        asm("v_cvt_pk_bf16_f32 %0, %1, %2" : "=v"(w0) : "v"(p0[0]), "v"(p0[1]));
        asm("v_cvt_pk_bf16_f32 %0, %1, %2" : "=v"(w1) : "v"(p0[2]), "v"(p0[3]));
        unsigned long long pk0 = (unsigned long long)w0 | ((unsigned long long)w1 << 32);
        *(unsigned long long*)(Pw + (size_t)c15 * 72 + nb * 16 + quad * 4) = pk0;
        asm("v_cvt_pk_bf16_f32 %0, %1, %2" : "=v"(w2) : "v"(p1[0]), "v"(p1[1]));
        asm("v_cvt_pk_bf16_f32 %0, %1, %2" : "=v"(w3) : "v"(p1[2]), "v"(p1[3]));
        unsigned long long pk1 = (unsigned long long)w2 | ((unsigned long long)w3 << 32);
        *(unsigned long long*)(Pw + (size_t)(16 + c15) * 72 + nb * 16 + quad * 4) = pk1;
      }
    }

    __syncthreads();  // D: B's stages landed (Vs/Ks[t+1]); P visible wave-locally

    // E: PV (unchanged; P layout [q][k] stride 72 identical)
    bf16x8 pf00 = *(const bf16x8*)(Pw + c15 * 72 + quad * 8);
    bf16x8 pf01 = *(const bf16x8*)(Pw + c15 * 72 + 32 + quad * 8);
    bf16x8 pf10 = *(const bf16x8*)(Pw + (16 + c15) * 72 + quad * 8);
    bf16x8 pf11 = *(const bf16x8*)(Pw + (16 + c15) * 72 + 32 + quad * 8);
#pragma unroll
    for (int nb = 0; nb < 8; ++nb) {
      int row = nb * 16 + c15;
      bf16x8 vf0 = *(const bf16x8*)(Vs + row * 64 + ((quad ^ (c15 & 7)) * 8));
      bf16x8 vf1 = *(const bf16x8*)(Vs + row * 64 + (((4 + quad) ^ (c15 & 7)) * 8));
      acc0[nb] = __builtin_amdgcn_mfma_f32_16x16x32_bf16(pf00, vf0, acc0[nb], 0, 0, 0);
      acc0[nb] = __builtin_amdgcn_mfma_f32_16x16x32_bf16(pf01, vf1, acc0[nb], 0, 0, 0);
      acc1[nb] = __builtin_amdgcn_mfma_f32_16x16x32_bf16(pf10, vf0, acc1[nb], 0, 0, 0);
      acc1[nb] = __builtin_amdgcn_mfma_f32_16x16x32_bf16(pf11, vf1, acc1[nb], 0, 0, 0);
    }
  }

  // lsum lives at lane c15 = q (all quads hold partial over their k); reduce quads.
  lsum0 += __shfl_xor(lsum0, 16);
  lsum0 += __shfl_xor(lsum0, 32);
  lsum1 += __shfl_xor(lsum1, 16);
  lsum1 += __shfl_xor(lsum1, 32);
  float inv0 = 1.0f / lsum0, inv1 = 1.0f / lsum1;
  float iv0[4], iv1[4];
#pragma unroll
  for (int r = 0; r < 4; ++r) {
    iv0[r] = __shfl(inv0, quad * 4 + r);
    iv1[r] = __shfl(inv1, quad * 4 + r);
  }
#pragma unroll
  for (int nb = 0; nb < 8; ++nb)
#pragma unroll
    for (int r = 0; r < 4; ++r) {
      size_t idx = ((size_t)b * S + q0 + quad * 4 + r) * 2048 + h * 128 + nb * 16 + c15;
      O[idx] = (__bf16)(acc0[nb][r] * iv0[r]);
      O[idx + (size_t)16 * 2048] = (__bf16)(acc1[nb][r] * iv1[r]);
    }
}

// ---------------- launch ----------------
extern "C" void kernel_launch(void* const* d_in, const int* in_sizes, int n_in,
                              void* d_out, int out_size, void* d_ws, size_t ws_size,
                              hipStream_t stream) {
  const float* x    = (const float*)d_in[0];
  const float* Wq   = (const float*)d_in[1];
  const float* Wk   = (const float*)d_in[2];
  const float* Wv   = (const float*)d_in[3];
  const float* Wo   = (const float*)d_in[4];
  const float* qw   = (const float*)d_in[5];
  const float* kw   = (const float*)d_in[6];
  const float* cosT = (const float*)d_in[7];
  const float* sinT = (const float*)d_in[8];
  const unsigned char* pad = (const unsigned char*)d_in[9];
  const int* win    = (const int*)d_in[10];

  char* ws = (char*)d_ws;
  __bf16* xb    = (__bf16*)(ws + 0);          // 4096x2048 bf16        (16 MB)
  __bf16* Wqkvt = (__bf16*)(ws + 16777216);   // 3072x2048 bf16        (12 MB)
  __bf16* Wot   = (__bf16*)(ws + 29360128);   // 2048x2048 bf16        (8 MB)
  __bf16* Qb    = (__bf16*)(ws + 37748736);   // [2][16][2048][128]    (16 MB)
  __bf16* Kb    = (__bf16*)(ws + 54525952);   // [2][4][2048][128]     (4 MB)
  __bf16* Vt    = (__bf16*)(ws + 58720256);   // [2][4][128][2048]     (4 MB)
  __bf16* Ob    = (__bf16*)(ws + 62914560);   // 4096x2048 bf16        (16 MB)
  unsigned char* pad64 = (unsigned char*)(ws + 79691776);  // [2][32]

  static int qkv_attr = (int)hipFuncSetAttribute(
      (const void*)gemm_qkv192, hipFuncAttributeMaxDynamicSharedMemorySize, 81920);
  (void)qkv_attr;
  static int bt_attr = (int)hipFuncSetAttribute(
      (const void*)gemm_bt128, hipFuncAttributeMaxDynamicSharedMemorySize, 65536);
  (void)bt_attr;
  static int at_attr = (int)hipFuncSetAttribute(
      (const void*)attn, hipFuncAttributeMaxDynamicSharedMemorySize, 67584);
  (void)at_attr;

  prep<<<dim3(288, 64, 1), dim3(32, 8, 1), 0, stream>>>(
      Wq, Wk, Wv, Wo, (const float4*)x, (const unsigned long long*)pad,
      Wqkvt, Wot, (bf16x4*)xb, pad64);

  gemm_qkv192<<<dim3(512, 1, 1), 512, 81920, stream>>>(xb, Wqkvt, Qb, Kb, Vt);

  norm_rope<<<20480, 256, 0, stream>>>(Qb, Kb, qw, kw, cosT, sinT);

  attn<<<dim3(64, 4, 2), 256, 67584, stream>>>(Qb, Kb, Vt, pad, pad64, win, Ob);

  gemm_bt128<<<dim3(512, 1, 1), 512, 65536, stream>>>(Ob, Wot, (float*)d_out);
}